// Round 10
// baseline (172.859 us; speedup 1.0000x reference)
//
#include <hip/hip_runtime.h>
#include <hip/hip_bf16.h>

#define NB 2
#define NS 512
#define ND 1024
#define NH 8
#define NDK 128
#define NDFF 4096
#define RPAD 64
#define LDSC 640              /* scores row stride: 512 scores + 128 qr */
#define BSROWS 1024           /* B*S */
#define NBH 16                /* B*H */

typedef __bf16 bf16x8 __attribute__((ext_vector_type(8)));
typedef __bf16 bf16x4 __attribute__((ext_vector_type(4)));
typedef float f32x4 __attribute__((ext_vector_type(4)));

#define BM 64
#define BN 64
#define BK 32

__device__ __forceinline__ void gload16(const void* g, void* l) {
    __builtin_amdgcn_global_load_lds(
        (const __attribute__((address_space(1))) void*)g,
        (__attribute__((address_space(3))) void*)l, 16, 0, 0);
}

// ---------------------------------------------------------------------------
// Counted-vmcnt pipelined MFMA GEMM, 64x64 tile, BK=32, 4 waves (each 32x32).
// LDS = 16 KB/block -> ~7 blocks/CU (TLP is the binding lever at these shapes).
// 2 LDS buffers; each wave's 2 loads/tile stay in flight across barriers
// (vmcnt(2)). Both-sides XOR swizzle within the 64-B row ((row&3)-keyed 16-B
// granule). Requires nt = Ksp/BK even >= 2.
// flags: 1=relu, 4=fused-rel-B (col tiles >= NS read Brel [128,128]),
//        8=QKV mode (col tiles >= 2048 write transposed V to vt).
// ---------------------------------------------------------------------------
__global__ __launch_bounds__(256, 6) void gemm64(
    const __bf16* __restrict__ A, const __bf16* __restrict__ Bt,
    const __bf16* __restrict__ Brel, __bf16* __restrict__ vt,
    float* __restrict__ Cf, __bf16* __restrict__ Cb,
    const float* __restrict__ bias,
    int Ksp, int lda, int ldb, int ldc,
    long sA, long sA2, int zdivA,
    long sB, long sB2, int zdivB,
    long sC, int nsplit, long sPart, int flags)
{
    __shared__ __bf16 As0[BM * BK];
    __shared__ __bf16 As1[BM * BK];
    __shared__ __bf16 Bs0[BN * BK];
    __shared__ __bf16 Bs1[BN * BK];

    // T1: XCD-bijective remap of the linear workgroup id (m204 formula).
    const unsigned gx = gridDim.x, gy = gridDim.y;
    const unsigned n = gx * gy * gridDim.z;
    const unsigned o = blockIdx.x + gx * (blockIdx.y + gy * blockIdx.z);
    const unsigned q = n >> 3, r = n & 7, xcd = o & 7;
    const unsigned nl = (xcd < r ? xcd * (q + 1) : r * (q + 1) + (xcd - r) * q) + (o >> 3);
    const unsigned bx = nl % gx, tmp = nl / gx;
    const unsigned by = tmp % gy, bz = tmp / gy;

    const int z = bz;
    const int bh = z / nsplit, sp = z - bh * nsplit;
    const long kbase = (long)sp * Ksp;
    A  += (long)(bh / zdivA) * sA + (long)(bh % zdivA) * sA2 + kbase;
    Bt += (long)(bh / zdivB) * sB + (long)(bh % zdivB) * sB2 + kbase;
    const long cbase = (long)bh * sC + (long)sp * sPart;

    const int tM = by * BM, tN = bx * BN;
    const int t = threadIdx.x, lane = t & 63, w = t >> 6;
    const int wr = w >> 1, wc = w & 1;

    const __bf16* Bbase = Bt;
    int ldbx = ldb, tNB = tN;
    if ((flags & 4) && tN >= NS) { Bbase = Brel + kbase; ldbx = 128; tNB = tN - NS; }

    // staging: row = lane>>2 within wave's 16-row chunk; 16-B source granule
    // pre-swizzled with (row&3) so linear LDS ends up XOR-swizzled.
    const int srow = lane >> 2;
    const int scolE = ((((lane & 3) << 4) ^ ((srow & 3) << 4)) >> 1);  // elements

    const __bf16* gA = A + (long)(tM + w * 16 + srow) * lda + scolE;
    const __bf16* gB = Bbase + (long)(tNB + w * 16 + srow) * ldbx + scolE;

    f32x4 acc[2][2];
#pragma unroll
    for (int m = 0; m < 2; ++m)
#pragma unroll
        for (int nn = 0; nn < 2; ++nn)
#pragma unroll
            for (int j = 0; j < 4; ++j) acc[m][nn][j] = 0.f;

    const int r16 = lane & 15;
    const int kq = (lane >> 4) * 8;     // 0,8,16,24 within BK=32
    const int xorE = (r16 & 3) * 8;     // read-side element XOR
    const int nt = Ksp / BK;

    auto STAGE = [&](__bf16* as, __bf16* bs, int k0) {
        gload16(gA + k0, (void*)&as[w * 16 * BK]);
        gload16(gB + k0, (void*)&bs[w * 16 * BK]);
    };
    auto COMPUTE = [&](const __bf16* as, const __bf16* bs) {
        __builtin_amdgcn_s_setprio(1);
        bf16x8 af[2], bv[2];
#pragma unroll
        for (int m = 0; m < 2; ++m)
            af[m] = *(const bf16x8*)&as[(wr * 32 + m * 16 + r16) * BK + (kq ^ xorE)];
#pragma unroll
        for (int nn = 0; nn < 2; ++nn)
            bv[nn] = *(const bf16x8*)&bs[(wc * 32 + nn * 16 + r16) * BK + (kq ^ xorE)];
#pragma unroll
        for (int m = 0; m < 2; ++m)
#pragma unroll
            for (int nn = 0; nn < 2; ++nn)
                acc[m][nn] = __builtin_amdgcn_mfma_f32_16x16x32_bf16(af[m], bv[nn], acc[m][nn], 0, 0, 0);
        __builtin_amdgcn_s_setprio(0);
    };

    STAGE(As0, Bs0, 0);        // 2 loads/wave
    STAGE(As1, Bs1, BK);       // 4 in flight
    for (int tt = 0; tt < nt; tt += 2) {
        asm volatile("s_waitcnt vmcnt(2)\n\ts_barrier" ::: "memory");   // buf0 ready
        COMPUTE(As0, Bs0);
        asm volatile("s_waitcnt lgkmcnt(0)\n\ts_barrier" ::: "memory");
        const bool more = (tt + 2 < nt);
        if (more) {
            STAGE(As0, Bs0, (tt + 2) * BK);
            asm volatile("s_waitcnt vmcnt(2)\n\ts_barrier" ::: "memory"); // buf1 ready
        } else {
            asm volatile("s_waitcnt vmcnt(0)\n\ts_barrier" ::: "memory");
        }
        COMPUTE(As1, Bs1);
        asm volatile("s_waitcnt lgkmcnt(0)\n\ts_barrier" ::: "memory");
        if (more) STAGE(As1, Bs1, (tt + 3) * BK);
    }

    const bool relu = (flags & 1) != 0;
    const bool vmode = (flags & 8) && (tN >= 2 * ND);   // uniform per block
#pragma unroll
    for (int m = 0; m < 2; ++m) {
        const int gr0 = tM + wr * 32 + m * 16 + (lane >> 4) * 4;
#pragma unroll
        for (int nn = 0; nn < 2; ++nn) {
            const int gc = tN + wc * 32 + nn * 16 + (lane & 15);
            const float bb = bias ? bias[gc] : 0.f;
            if (vmode) {
                // V col-tile: write transposed vt[b][h][d][i..i+3]
                const int hd = gc - 2 * ND;
                const int b = gr0 >> 9, i = gr0 & 511;
                bf16x4 o;
#pragma unroll
                for (int j = 0; j < 4; ++j) o[j] = (__bf16)(acc[m][nn][j] + bb);
                *(bf16x4*)&vt[(((long)b * NH + (hd >> 7)) * NDK + (hd & 127)) * NS + i] = o;
            } else {
#pragma unroll
                for (int j = 0; j < 4; ++j) {
                    float v = acc[m][nn][j] + bb;
                    if (relu) v = fmaxf(v, 0.f);
                    const long idx = cbase + (long)(gr0 + j) * ldc + gc;
                    if (Cb) Cb[idx] = (__bf16)v;
                    else Cf[idx] = v;
                }
            }
        }
    }
}

// ---------------------------------------------------------------------------
// Fused prep: all fp32->bf16 weight transposes + bias pack + relk pad + LN1.
// grid.x = 13396 blocks of (32,8).
// ---------------------------------------------------------------------------
__global__ void prep_weights(
    const float* __restrict__ Wq, const float* __restrict__ Wk,
    const float* __restrict__ Wv, const float* __restrict__ Wo,
    const float* __restrict__ W1, const float* __restrict__ W2,
    const float* __restrict__ relv,
    const float* __restrict__ bq, const float* __restrict__ bk,
    const float* __restrict__ bv, const float* __restrict__ relk,
    const float* __restrict__ x, const float* __restrict__ ln1g,
    const float* __restrict__ ln1b,
    __bf16* __restrict__ WqkvT, __bf16* __restrict__ WoT,
    __bf16* __restrict__ W1T, __bf16* __restrict__ W2T,
    __bf16* __restrict__ relvT, float* __restrict__ biasqkv,
    __bf16* __restrict__ relkT, __bf16* __restrict__ h1, int R)
{
    const int tile = blockIdx.x;
    const int t = threadIdx.y * 32 + threadIdx.x;

    if (tile >= 12372) {   // LN1 row
        const long row = tile - 12372;
        const float* xr = x + row * ND;
        float4 v = reinterpret_cast<const float4*>(xr)[t];
        float s = v.x + v.y + v.z + v.w;
        float s2 = v.x * v.x + v.y * v.y + v.z * v.z + v.w * v.w;
#pragma unroll
        for (int o = 32; o > 0; o >>= 1) {
            s += __shfl_xor(s, o, 64);
            s2 += __shfl_xor(s2, o, 64);
        }
        __shared__ float red[8];
        const int lane = t & 63, wv = t >> 6;
        if (lane == 0) { red[wv] = s; red[4 + wv] = s2; }
        __syncthreads();
        s = red[0] + red[1] + red[2] + red[3];
        s2 = red[4] + red[5] + red[6] + red[7];
        const float mean = s * (1.f / ND);
        const float var = s2 * (1.f / ND) - mean * mean;
        const float rs = rsqrtf(var + 1e-5f);
        const float xv[4] = {v.x, v.y, v.z, v.w};
        bf16x4 o;
#pragma unroll
        for (int j = 0; j < 4; ++j) {
            const int c = t * 4 + j;
            o[j] = (__bf16)((xv[j] - mean) * rs * ln1g[c] + ln1b[c]);
        }
        *(bf16x4*)&h1[row * ND + t * 4] = o;
        return;
    }
    if (tile >= 12296) {   // bias pack + relk pad (flat)
        const int ft = (tile - 12296) * 256 + t;
        if (ft < ND) biasqkv[ft] = bq[ft];
        else if (ft < 2 * ND) biasqkv[ft] = bk[ft - ND];
        else if (ft < 3 * ND) biasqkv[ft] = bv[ft - 2 * ND];
        else {
            const int idx = ft - 3 * ND;
            if (idx < 128 * NDK) {
                const int r = idx / NDK;
                relkT[idx] = (r < R) ? (__bf16)relk[idx] : (__bf16)0.f;
            }
        }
        return;
    }
    const float* src; __bf16* dst;
    int rows_in, cols_in, ldo, kx, ny;
    if (tile < 4096) {
        const int m = tile >> 10, r = tile & 1023;
        kx = r & 31; ny = r >> 5;
        rows_in = 1024; cols_in = 1024; ldo = 1024;
        src = m == 0 ? Wq : m == 1 ? Wk : m == 2 ? Wv : Wo;
        dst = m == 3 ? WoT : WqkvT + (size_t)m * 1024 * 1024;
    } else if (tile < 8192) {
        const int r = tile - 4096;
        kx = r & 31; ny = r >> 5;
        rows_in = 1024; cols_in = 4096; ldo = 1024; src = W1; dst = W1T;
    } else if (tile < 12288) {
        const int r = tile - 8192;
        kx = r & 127; ny = r >> 7;
        rows_in = 4096; cols_in = 1024; ldo = 4096; src = W2; dst = W2T;
    } else {
        const int r = tile - 12288;
        kx = r & 1; ny = r >> 1;
        rows_in = R; cols_in = 128; ldo = 64; src = relv; dst = relvT;
    }

    __shared__ float tl[32][33];
    const int k0 = kx * 32, n0 = ny * 32;
    const int tx = threadIdx.x, ty = threadIdx.y;
#pragma unroll
    for (int dy = 0; dy < 32; dy += 8) {
        const int k = k0 + ty + dy, nn = n0 + tx;
        tl[ty + dy][tx] = (k < rows_in && nn < cols_in) ? src[(long)k * cols_in + nn] : 0.f;
    }
    __syncthreads();
#pragma unroll
    for (int dy = 0; dy < 32; dy += 8) {
        const int nn = n0 + ty + dy, k = k0 + tx;
        if (nn < cols_in && k < ldo) dst[(long)nn * ldo + k] = (__bf16)tl[tx][ty + dy];
    }
}

// ---------------------------------------------------------------------------
// Fused softmax, loops over all 8 heads per (i,b) block: relation/mask rows
// loaded ONCE. scores bf16, rows LDSC=640 wide ([512,640) = qr table).
// ---------------------------------------------------------------------------
__global__ __launch_bounds__(256) void softmax_rel(
    const __bf16* __restrict__ scores,
    const int* __restrict__ relation, const int* __restrict__ mask,
    __bf16* __restrict__ attn, __bf16* __restrict__ attnR,
    float* __restrict__ loss_part, const int* __restrict__ sep_p)
{
    const int i = blockIdx.x, b = blockIdx.y;
    const int t = threadIdx.x;
    const int* rrow = relation + ((long)b * NS + i) * NS;
    const int* mrow = mask + ((long)b * NS + i) * NS;
    const int r0 = rrow[t], r1 = rrow[t + 256];
    const int m0 = mrow[t], m1 = mrow[t + 256];
    const int sep = *sep_p;
    const int lane = t & 63, wv = t >> 6;

    __shared__ float qrl[RPAD];
    __shared__ float bins[RPAD];
    __shared__ float red[4];

    const float sc = 0.088388347648318447f;  // 1/sqrt(128)
    float lsum = 0.f;

#pragma unroll 1
    for (int h = 0; h < NH; ++h) {
        const long bh = (long)(b * NH + h);
        const __bf16* srow = scores + (bh * NS + i) * LDSC;
        __bf16* arow = attn + (bh * NS + i) * NS;
        __bf16* aRrow = attnR + (bh * NS + i) * RPAD;

        if (t < RPAD) { qrl[t] = (float)srow[NS + t]; bins[t] = 0.f; }
        __syncthreads();

        float v0 = ((float)srow[t] + qrl[r0]) * sc;
        float v1 = ((float)srow[t + 256] + qrl[r1]) * sc;
        if (m0 == 0) v0 = -1e9f;
        if (m1 == 0) v1 = -1e9f;

        float mx = fmaxf(v0, v1);
#pragma unroll
        for (int o = 32; o > 0; o >>= 1) mx = fmaxf(mx, __shfl_xor(mx, o, 64));
        if (lane == 0) red[wv] = mx;
        __syncthreads();
        mx = fmaxf(fmaxf(red[0], red[1]), fmaxf(red[2], red[3]));
        __syncthreads();

        const float e0 = __expf(v0 - mx), e1 = __expf(v1 - mx);
        float sm = e0 + e1;
#pragma unroll
        for (int o = 32; o > 0; o >>= 1) sm += __shfl_xor(sm, o, 64);
        if (lane == 0) red[wv] = sm;
        __syncthreads();
        sm = red[0] + red[1] + red[2] + red[3];

        const float inv = 1.f / sm;
        const float a0 = e0 * inv, a1 = e1 * inv;
        arow[t] = (__bf16)a0;
        arow[t + 256] = (__bf16)a1;
        atomicAdd(&bins[r0], a0);
        atomicAdd(&bins[r1], a1);
        if (t < sep) lsum += a0;
        if (t + 256 < sep) lsum += a1;
        __syncthreads();
        if (t < RPAD) aRrow[t] = (__bf16)bins[t];
        __syncthreads();
    }

#pragma unroll
    for (int o = 32; o > 0; o >>= 1) lsum += __shfl_xor(lsum, o, 64);
    if (lane == 0) red[wv] = lsum;
    __syncthreads();
    if (t == 0) loss_part[(long)b * NS + i] = red[0] + red[1] + red[2] + red[3];
}

// ctx split-K(2) reduce + fused attnR@rel_v + merge_heads -> ctxm bf16 [B*S, D]
__global__ __launch_bounds__(256) void ctx_reduce(
    const float* __restrict__ P, const __bf16* __restrict__ attnR,
    const __bf16* __restrict__ relvT, __bf16* __restrict__ ctxm)
{
    const int idx = blockIdx.x * 256 + threadIdx.x;
    const int d = idx & 127;
    const int i = (idx >> 7) & 511;
    const int h = (idx >> 16) & 7;
    const int b = idx >> 19;
    const long sP = (long)NBH * NS * NDK;
    float s = P[idx] + P[idx + sP];

    const bf16x8* ar = (const bf16x8*)(attnR + ((long)(idx >> 16) * NS + i) * RPAD);
    const bf16x8* rv = (const bf16x8*)(relvT + (long)d * RPAD);
    float acc = 0.f;
#pragma unroll
    for (int q = 0; q < 8; ++q) {
        bf16x8 a = ar[q], vv = rv[q];
#pragma unroll
        for (int j = 0; j < 8; ++j) acc += (float)a[j] * (float)vv[j];
    }
    ctxm[((long)(b * NS + i)) * ND + h * NDK + d] = (__bf16)(s + acc);
}

// Wo split-K(2) reduce + residual + bias, fused LN2 -> out fp32 + h2 bf16.
__global__ __launch_bounds__(256) void wo_reduce_ln(
    const float* __restrict__ P, const float* __restrict__ x,
    const float* __restrict__ bo, const float* __restrict__ g,
    const float* __restrict__ bb, float* __restrict__ out,
    __bf16* __restrict__ h2)
{
    const int row = blockIdx.x;
    const int t = threadIdx.x;
    const long i4 = (long)row * 256 + t;
    const long sP = (long)BSROWS * ND / 4;
    const float4* P4 = (const float4*)P;
    float4 s = P4[i4];
    const float4 t1 = P4[i4 + sP];
    s.x += t1.x; s.y += t1.y; s.z += t1.z; s.w += t1.w;
    const int col = t * 4;
    const float4 xv = ((const float4*)x)[i4];
    const float4 bv = *(const float4*)&bo[col];
    float4 o;
    o.x = s.x + xv.x + bv.x; o.y = s.y + xv.y + bv.y;
    o.z = s.z + xv.z + bv.z; o.w = s.w + xv.w + bv.w;
    ((float4*)out)[i4] = o;

    float sum = o.x + o.y + o.z + o.w;
    float sum2 = o.x * o.x + o.y * o.y + o.z * o.z + o.w * o.w;
#pragma unroll
    for (int of = 32; of > 0; of >>= 1) {
        sum += __shfl_xor(sum, of, 64);
        sum2 += __shfl_xor(sum2, of, 64);
    }
    __shared__ float red[8];
    const int lane = t & 63, wv = t >> 6;
    if (lane == 0) { red[wv] = sum; red[4 + wv] = sum2; }
    __syncthreads();
    sum = red[0] + red[1] + red[2] + red[3];
    sum2 = red[4] + red[5] + red[6] + red[7];
    const float mean = sum * (1.f / ND);
    const float var = sum2 * (1.f / ND) - mean * mean;
    const float rs = rsqrtf(var + 1e-5f);
    const float ov[4] = {o.x, o.y, o.z, o.w};
    bf16x4 hb;
#pragma unroll
    for (int j = 0; j < 4; ++j)
        hb[j] = (__bf16)((ov[j] - mean) * rs * g[col + j] + bb[col + j]);
    *(bf16x4*)&h2[(long)row * ND + col] = hb;
}

// FFN2 split-K(2) reduce: out += b2 + sum_2 partials. Block 0 also finalizes loss.
__global__ __launch_bounds__(256) void ffn2_reduce(
    const float* __restrict__ P, const float* __restrict__ b2, float* __restrict__ out,
    const float* __restrict__ loss_part, const float* __restrict__ hist,
    const int* __restrict__ sep_p, float* __restrict__ out_loss)
{
    const int i4 = blockIdx.x * 256 + threadIdx.x;
    const long sP = (long)BSROWS * ND / 4;
    const float4* P4 = (const float4*)P;
    float4 s = P4[i4];
    const float4 t1 = P4[i4 + sP];
    s.x += t1.x; s.y += t1.y; s.z += t1.z; s.w += t1.w;
    const int col = (i4 * 4) & (ND - 1);
    const float4 bv = *(const float4*)&b2[col];
    float4 o = ((float4*)out)[i4];
    o.x += s.x + bv.x; o.y += s.y + bv.y;
    o.z += s.z + bv.z; o.w += s.w + bv.w;
    ((float4*)out)[i4] = o;

    if (blockIdx.x == 0) {
        const int t = threadIdx.x;
        const float4 v = ((const float4*)loss_part)[t];   // 1024 floats total
        float ls = v.x + v.y + v.z + v.w;
#pragma unroll
        for (int of = 32; of > 0; of >>= 1) ls += __shfl_xor(ls, of, 64);
        __shared__ float red[4];
        if ((t & 63) == 0) red[t >> 6] = ls;
        __syncthreads();
        if (t == 0) {
            const int sep = *sep_p;
            const float total = red[0] + red[1] + red[2] + red[3];
            const float denom = (float)NB * NH * NS * (float)(sep > 0 ? sep : 1);
            out_loss[0] = (sep > 0) ? hist[0] * total / denom : 0.f;
        }
    }
}

// ---------------------------------------------------------------------------
static inline int cdiv(int a, int b) { return (a + b - 1) / b; }

extern "C" void kernel_launch(void* const* d_in, const int* in_sizes, int n_in,
                              void* d_out, int out_size, void* d_ws, size_t ws_size,
                              hipStream_t stream)
{
    const float* x      = (const float*)d_in[0];
    const int* relation = (const int*)d_in[1];
    const int* mask     = (const int*)d_in[2];
    const int* sep_p    = (const int*)d_in[3];
    const float* hist   = (const float*)d_in[4];
    const float* Wq = (const float*)d_in[5],  *bq = (const float*)d_in[6];
    const float* Wk = (const float*)d_in[7],  *bk = (const float*)d_in[8];
    const float* Wv = (const float*)d_in[9],  *bv = (const float*)d_in[10];
    const float* Wo = (const float*)d_in[11], *bo = (const float*)d_in[12];
    const float* relk = (const float*)d_in[13];
    const float* relv = (const float*)d_in[14];
    const float* ln1g = (const float*)d_in[15], *ln1b = (const float*)d_in[16];
    const float* ln2g = (const float*)d_in[17], *ln2b = (const float*)d_in[18];
    const float* W1 = (const float*)d_in[19], *b1 = (const float*)d_in[20];
    const float* W2 = (const float*)d_in[21], *b2 = (const float*)d_in[22];
    const int R = in_sizes[13] / NDK;  // 51

    float* out = (float*)d_out;
    float* out_loss = out + (long)BSROWS * ND;

    char* p = (char*)d_ws;
    auto alloc = [&](size_t bytes) -> void* {
        void* r = (void*)p;
        p += (bytes + 255) & ~(size_t)255;
        return r;
    };
    __bf16* WqkvT   = (__bf16*)alloc((size_t)3 * ND * ND * 2);
    __bf16* WoT     = (__bf16*)alloc((size_t)ND * ND * 2);
    __bf16* W1T     = (__bf16*)alloc((size_t)NDFF * ND * 2);
    __bf16* W2T     = (__bf16*)alloc((size_t)ND * NDFF * 2);
    __bf16* relkT   = (__bf16*)alloc((size_t)128 * NDK * 2);
    __bf16* relvT   = (__bf16*)alloc((size_t)NDK * RPAD * 2);
    float*  biasqkv = (float*)alloc((size_t)3 * ND * 4);
    __bf16* h1      = (__bf16*)alloc((size_t)BSROWS * ND * 2);
    __bf16* qkvb    = (__bf16*)alloc((size_t)BSROWS * 3 * ND * 2);
    __bf16* vt      = (__bf16*)alloc((size_t)NBH * NDK * NS * 2);
    __bf16* attnb   = (__bf16*)alloc((size_t)NBH * NS * NS * 2);
    __bf16* attnR   = (__bf16*)alloc((size_t)NBH * NS * RPAD * 2);
    __bf16* ctxm    = (__bf16*)alloc((size_t)BSROWS * ND * 2);
    __bf16* h2      = (__bf16*)alloc((size_t)BSROWS * ND * 2);
    __bf16* F1      = (__bf16*)alloc((size_t)BSROWS * NDFF * 2);
    float*  loss_part = (float*)alloc((size_t)NB * NS * 4);
    float*  arena   = (float*)alloc((size_t)64 * 1024 * 1024);
    // arena aliasing (lifetimes disjoint):
    __bf16* scoresb = (__bf16*)arena;                   // 10.5MB, dead after softmax
    float* ctxPart  = arena + (size_t)3 * 1024 * 1024;  // [12,20)MB
    float* woPart   = arena;                            // [0,8)MB
    float* f2Part   = arena + (size_t)2 * 1024 * 1024;  // [8,16)MB

    const dim3 tb(32, 8);
    // fused weight prep + LN1 (13396 blocks)
    prep_weights<<<13396, tb, 0, stream>>>(Wq, Wk, Wv, Wo, W1, W2, relv,
                                           bq, bk, bv, relk, x, ln1g, ln1b,
                                           WqkvT, WoT, W1T, W2T, relvT,
                                           biasqkv, relkT, h1, R);

    // QKV: [1024,1024] @ [3072,1024]^T -> qkvb bf16 + fused V-transpose -> vt
    // (768 blocks, nt=32)
    gemm64<<<dim3(48, 16, 1), 256, 0, stream>>>(
        h1, WqkvT, nullptr, vt, nullptr, qkvb, biasqkv,
        ND, ND, ND, 3 * ND,
        0, 0, 1, 0, 0, 1, 0, 1, 0, 8);

    // scores+qr fused: per-head q @ [k^T | relk^T] -> scoresb bf16 [512,640]
    // (1280 blocks, nt=4)
    gemm64<<<dim3(10, 8, NBH), 256, 0, stream>>>(
        qkvb, qkvb + ND, relkT, nullptr, nullptr, scoresb, nullptr,
        NDK, 3 * ND, 3 * ND, LDSC,
        (long)NS * 3 * ND, NDK, NH,
        (long)NS * 3 * ND, NDK, NH,
        (long)NS * LDSC, 1, 0, 4);

    softmax_rel<<<dim3(NS, NB), 256, 0, stream>>>(
        scoresb, relation, mask, attnb, attnR, loss_part, sep_p);

    // ctx = attn @ v : split-K x2 (Ksp=256, nt=8), 512 blocks
    gemm64<<<dim3(2, 8, NBH * 2), 256, 0, stream>>>(
        attnb, vt, nullptr, nullptr, ctxPart, nullptr, nullptr,
        256, NS, NS, NDK,
        (long)NS * NS, 0, 1,
        (long)NDK * NS, 0, 1,
        (long)NS * NDK, 2, (long)NBH * NS * NDK, 0);

    ctx_reduce<<<4096, 256, 0, stream>>>(ctxPart, attnR, relvT, ctxm);

    // attn_out partials: ctxm @ Wo, split-K x2 (Ksp=512, nt=16), 512 blocks
    gemm64<<<dim3(16, 16, 2), 256, 0, stream>>>(
        ctxm, WoT, nullptr, nullptr, woPart, nullptr, nullptr,
        512, ND, ND, ND,
        0, 0, 1, 0, 0, 1,
        0, 2, (long)BSROWS * ND, 0);

    // fused: out = x + bo + sum_2 partials; h2 = LN2(out)
    wo_reduce_ln<<<BSROWS, 256, 0, stream>>>(woPart, x, bo, ln2g, ln2b, out, h2);

    // FFN1: relu(h2 @ W1 + b1) -> F1 bf16 (1024 blocks, nt=32)
    gemm64<<<dim3(64, 16, 1), 256, 0, stream>>>(
        h2, W1T, nullptr, nullptr, nullptr, F1, b1,
        ND, ND, ND, NDFF,
        0, 0, 1, 0, 0, 1, 0, 1, 0, 1);

    // FFN2 partials: F1 @ W2, split-K x2 (Ksp=2048, nt=64), 512 blocks
    gemm64<<<dim3(16, 16, 2), 256, 0, stream>>>(
        F1, W2T, nullptr, nullptr, f2Part, nullptr, nullptr,
        2048, NDFF, NDFF, ND,
        0, 0, 1, 0, 0, 1,
        0, 2, (long)BSROWS * ND, 0);

    // FFN2 reduce + fused loss finalize
    ffn2_reduce<<<1024, 256, 0, stream>>>(f2Part, b2, out,
                                          loss_part, hist, sep_p, out_loss);
}

// Round 11
// 159.169 us; speedup vs baseline: 1.0860x; 1.0860x over previous
//
#include <hip/hip_runtime.h>
#include <hip/hip_bf16.h>

#define NB 2
#define NS 512
#define ND 1024
#define NH 8
#define NDK 128
#define NDFF 4096
#define RPAD 64
#define LDSC 640              /* scores row stride: 512 scores + 128 qr */
#define BSROWS 1024           /* B*S */
#define NBH 16                /* B*H */

typedef __bf16 bf16x8 __attribute__((ext_vector_type(8)));
typedef __bf16 bf16x4 __attribute__((ext_vector_type(4)));
typedef float f32x4 __attribute__((ext_vector_type(4)));

#define BM 64
#define BN 64
#define BK 64

__device__ __forceinline__ void gload16(const void* g, void* l) {
    __builtin_amdgcn_global_load_lds(
        (const __attribute__((address_space(1))) void*)g,
        (__attribute__((address_space(3))) void*)l, 16, 0, 0);
}

// ---------------------------------------------------------------------------
// Counted-vmcnt pipelined MFMA GEMM, 64x64 tile, BK=64, 4 waves (each 32x32).
// R9-proven config: 32 KB LDS/block, 4-5 blocks/CU, vmcnt(4) cross-barrier
// prefetch, both-sides XOR swizzle. Requires nt = Ksp/BK even >= 2.
// flags: 1=relu, 4=fused-rel-B (col tiles >= NS read Brel [128,128]),
//        8=QKV mode (col tiles >= 2048 write transposed V to vt),
//        16=ctx mode (epilogue adds attnR@relvT and writes merged ctxm).
// ---------------------------------------------------------------------------
__global__ __launch_bounds__(256, 4) void gemm64(
    const __bf16* __restrict__ A, const __bf16* __restrict__ Bt,
    const __bf16* __restrict__ Brel, __bf16* __restrict__ vt,
    const __bf16* __restrict__ arP, const __bf16* __restrict__ rvP,
    __bf16* __restrict__ ctxmP,
    float* __restrict__ Cf, __bf16* __restrict__ Cb,
    const float* __restrict__ bias,
    int Ksp, int lda, int ldb, int ldc,
    long sA, long sA2, int zdivA,
    long sB, long sB2, int zdivB,
    long sC, int nsplit, long sPart, int flags)
{
    __shared__ __bf16 As0[BM * BK];
    __shared__ __bf16 As1[BM * BK];
    __shared__ __bf16 Bs0[BN * BK];
    __shared__ __bf16 Bs1[BN * BK];

    // T1: XCD-bijective remap of the linear workgroup id (m204 formula).
    const unsigned gx = gridDim.x, gy = gridDim.y;
    const unsigned n = gx * gy * gridDim.z;
    const unsigned o = blockIdx.x + gx * (blockIdx.y + gy * blockIdx.z);
    const unsigned q = n >> 3, r = n & 7, xcd = o & 7;
    const unsigned nl = (xcd < r ? xcd * (q + 1) : r * (q + 1) + (xcd - r) * q) + (o >> 3);
    const unsigned bx = nl % gx, tmp = nl / gx;
    const unsigned by = tmp % gy, bz = tmp / gy;

    const int z = bz;
    const int bh = z / nsplit, sp = z - bh * nsplit;
    const long kbase = (long)sp * Ksp;
    A  += (long)(bh / zdivA) * sA + (long)(bh % zdivA) * sA2 + kbase;
    Bt += (long)(bh / zdivB) * sB + (long)(bh % zdivB) * sB2 + kbase;
    const long cbase = (long)bh * sC + (long)sp * sPart;

    const int tM = by * BM, tN = bx * BN;
    const int t = threadIdx.x, lane = t & 63, w = t >> 6;
    const int wr = w >> 1, wc = w & 1;

    const __bf16* Bbase = Bt;
    int ldbx = ldb, tNB = tN;
    if ((flags & 4) && tN >= NS) { Bbase = Brel + kbase; ldbx = 128; tNB = tN - NS; }

    // staging: row = lane>>3 within 8-row chunk; source col pre-swizzled so
    // linear LDS ends up row-XOR-swizzled: c_src = c_lds ^ ((row&7)<<4) bytes
    const int srow = lane >> 3;
    const int scolE = ((((lane & 7) << 4) ^ (srow << 4)) >> 1);

    const __bf16* gA = A + (long)(tM + srow) * lda + scolE;
    const __bf16* gB = Bbase + (long)(tNB + srow) * ldbx + scolE;

    f32x4 acc[2][2];
#pragma unroll
    for (int m = 0; m < 2; ++m)
#pragma unroll
        for (int nn = 0; nn < 2; ++nn)
#pragma unroll
            for (int j = 0; j < 4; ++j) acc[m][nn][j] = 0.f;

    const int r16 = lane & 15;
    const int kq = (lane >> 4) * 8;
    const int xorE = (r16 & 7) * 8;
    const int nt = Ksp / BK;

    auto STAGE = [&](__bf16* as, __bf16* bs, int k0) {
#pragma unroll
        for (int i = 0; i < 2; ++i) {
            const int rr = (w + i * 4) * 8;   // wave-uniform 8-row chunk base
            gload16(gA + (long)rr * lda + k0, (void*)&as[rr * BK]);
            gload16(gB + (long)rr * ldbx + k0, (void*)&bs[rr * BK]);
        }
    };
    auto COMPUTE = [&](const __bf16* as, const __bf16* bs) {
        __builtin_amdgcn_s_setprio(1);
#pragma unroll
        for (int ks = 0; ks < 2; ++ks) {
            bf16x8 af[2], bv[2];
#pragma unroll
            for (int m = 0; m < 2; ++m)
                af[m] = *(const bf16x8*)&as[(wr * 32 + m * 16 + r16) * BK + ((ks * 32 + kq) ^ xorE)];
#pragma unroll
            for (int nn = 0; nn < 2; ++nn)
                bv[nn] = *(const bf16x8*)&bs[(wc * 32 + nn * 16 + r16) * BK + ((ks * 32 + kq) ^ xorE)];
#pragma unroll
            for (int m = 0; m < 2; ++m)
#pragma unroll
                for (int nn = 0; nn < 2; ++nn)
                    acc[m][nn] = __builtin_amdgcn_mfma_f32_16x16x32_bf16(af[m], bv[nn], acc[m][nn], 0, 0, 0);
        }
        __builtin_amdgcn_s_setprio(0);
    };

    STAGE(As0, Bs0, 0);        // 4 loads/wave
    STAGE(As1, Bs1, BK);       // 8 in flight
    for (int tt = 0; tt < nt; tt += 2) {
        asm volatile("s_waitcnt vmcnt(4)\n\ts_barrier" ::: "memory");   // buf0 ready
        COMPUTE(As0, Bs0);
        asm volatile("s_waitcnt lgkmcnt(0)\n\ts_barrier" ::: "memory");
        const bool more = (tt + 2 < nt);
        if (more) {
            STAGE(As0, Bs0, (tt + 2) * BK);
            asm volatile("s_waitcnt vmcnt(4)\n\ts_barrier" ::: "memory"); // buf1 ready
        } else {
            asm volatile("s_waitcnt vmcnt(0)\n\ts_barrier" ::: "memory");
        }
        COMPUTE(As1, Bs1);
        asm volatile("s_waitcnt lgkmcnt(0)\n\ts_barrier" ::: "memory");
        if (more) STAGE(As1, Bs1, (tt + 3) * BK);
    }

    if (flags & 16) {
        // ctx mode: out = acc + attnR[bh][row] . relvT[gc]; write merged heads.
        const int b = bh >> 3, h = bh & 7;
#pragma unroll
        for (int nn = 0; nn < 2; ++nn) {
            const int gc = tN + wc * 32 + nn * 16 + (lane & 15);   // d in [0,128)
            bf16x8 rv[8];
#pragma unroll
            for (int qq = 0; qq < 8; ++qq)
                rv[qq] = ((const bf16x8*)&rvP[(long)gc * RPAD])[qq];
#pragma unroll
            for (int m = 0; m < 2; ++m) {
                const int gr0 = tM + wr * 32 + m * 16 + (lane >> 4) * 4;
#pragma unroll
                for (int j = 0; j < 4; ++j) {
                    const int row = gr0 + j;
                    const bf16x8* ar8 = (const bf16x8*)&arP[((long)bh * NS + row) * RPAD];
                    float d = 0.f;
#pragma unroll
                    for (int qq = 0; qq < 8; ++qq) {
                        const bf16x8 a = ar8[qq], vv = rv[qq];
#pragma unroll
                        for (int e = 0; e < 8; ++e) d += (float)a[e] * (float)vv[e];
                    }
                    ctxmP[((long)(b * NS + row)) * ND + h * NDK + gc] =
                        (__bf16)(acc[m][nn][j] + d);
                }
            }
        }
        return;
    }

    const bool relu = (flags & 1) != 0;
    const bool vmode = (flags & 8) && (tN >= 2 * ND);   // uniform per block
#pragma unroll
    for (int m = 0; m < 2; ++m) {
        const int gr0 = tM + wr * 32 + m * 16 + (lane >> 4) * 4;
#pragma unroll
        for (int nn = 0; nn < 2; ++nn) {
            const int gc = tN + wc * 32 + nn * 16 + (lane & 15);
            const float bb = bias ? bias[gc] : 0.f;
            if (vmode) {
                // V col-tile: write transposed vt[b][h][d][i..i+3]
                const int hd = gc - 2 * ND;
                const int b = gr0 >> 9, i = gr0 & 511;
                bf16x4 ov;
#pragma unroll
                for (int j = 0; j < 4; ++j) ov[j] = (__bf16)(acc[m][nn][j] + bb);
                *(bf16x4*)&vt[(((long)b * NH + (hd >> 7)) * NDK + (hd & 127)) * NS + i] = ov;
            } else {
#pragma unroll
                for (int j = 0; j < 4; ++j) {
                    float v = acc[m][nn][j] + bb;
                    if (relu) v = fmaxf(v, 0.f);
                    const long idx = cbase + (long)(gr0 + j) * ldc + gc;
                    if (Cb) Cb[idx] = (__bf16)v;
                    else Cf[idx] = v;
                }
            }
        }
    }
}

// ---------------------------------------------------------------------------
// Fused prep: all fp32->bf16 weight transposes + bias pack + relk pad + LN1.
// grid.x = 13396 blocks of (32,8).
// ---------------------------------------------------------------------------
__global__ void prep_weights(
    const float* __restrict__ Wq, const float* __restrict__ Wk,
    const float* __restrict__ Wv, const float* __restrict__ Wo,
    const float* __restrict__ W1, const float* __restrict__ W2,
    const float* __restrict__ relv,
    const float* __restrict__ bq, const float* __restrict__ bk,
    const float* __restrict__ bv, const float* __restrict__ relk,
    const float* __restrict__ x, const float* __restrict__ ln1g,
    const float* __restrict__ ln1b,
    __bf16* __restrict__ WqkvT, __bf16* __restrict__ WoT,
    __bf16* __restrict__ W1T, __bf16* __restrict__ W2T,
    __bf16* __restrict__ relvT, float* __restrict__ biasqkv,
    __bf16* __restrict__ relkT, __bf16* __restrict__ h1, int R)
{
    const int tile = blockIdx.x;
    const int t = threadIdx.y * 32 + threadIdx.x;

    if (tile >= 12372) {   // LN1 row
        const long row = tile - 12372;
        const float* xr = x + row * ND;
        float4 v = reinterpret_cast<const float4*>(xr)[t];
        float s = v.x + v.y + v.z + v.w;
        float s2 = v.x * v.x + v.y * v.y + v.z * v.z + v.w * v.w;
#pragma unroll
        for (int o = 32; o > 0; o >>= 1) {
            s += __shfl_xor(s, o, 64);
            s2 += __shfl_xor(s2, o, 64);
        }
        __shared__ float red[8];
        const int lane = t & 63, wv = t >> 6;
        if (lane == 0) { red[wv] = s; red[4 + wv] = s2; }
        __syncthreads();
        s = red[0] + red[1] + red[2] + red[3];
        s2 = red[4] + red[5] + red[6] + red[7];
        const float mean = s * (1.f / ND);
        const float var = s2 * (1.f / ND) - mean * mean;
        const float rs = rsqrtf(var + 1e-5f);
        const float xv[4] = {v.x, v.y, v.z, v.w};
        bf16x4 o;
#pragma unroll
        for (int j = 0; j < 4; ++j) {
            const int c = t * 4 + j;
            o[j] = (__bf16)((xv[j] - mean) * rs * ln1g[c] + ln1b[c]);
        }
        *(bf16x4*)&h1[row * ND + t * 4] = o;
        return;
    }
    if (tile >= 12296) {   // bias pack + relk pad (flat)
        const int ft = (tile - 12296) * 256 + t;
        if (ft < ND) biasqkv[ft] = bq[ft];
        else if (ft < 2 * ND) biasqkv[ft] = bk[ft - ND];
        else if (ft < 3 * ND) biasqkv[ft] = bv[ft - 2 * ND];
        else {
            const int idx = ft - 3 * ND;
            if (idx < 128 * NDK) {
                const int r = idx / NDK;
                relkT[idx] = (r < R) ? (__bf16)relk[idx] : (__bf16)0.f;
            }
        }
        return;
    }
    const float* src; __bf16* dst;
    int rows_in, cols_in, ldo, kx, ny;
    if (tile < 4096) {
        const int m = tile >> 10, r = tile & 1023;
        kx = r & 31; ny = r >> 5;
        rows_in = 1024; cols_in = 1024; ldo = 1024;
        src = m == 0 ? Wq : m == 1 ? Wk : m == 2 ? Wv : Wo;
        dst = m == 3 ? WoT : WqkvT + (size_t)m * 1024 * 1024;
    } else if (tile < 8192) {
        const int r = tile - 4096;
        kx = r & 31; ny = r >> 5;
        rows_in = 1024; cols_in = 4096; ldo = 1024; src = W1; dst = W1T;
    } else if (tile < 12288) {
        const int r = tile - 8192;
        kx = r & 127; ny = r >> 7;
        rows_in = 4096; cols_in = 1024; ldo = 4096; src = W2; dst = W2T;
    } else {
        const int r = tile - 12288;
        kx = r & 1; ny = r >> 1;
        rows_in = R; cols_in = 128; ldo = 64; src = relv; dst = relvT;
    }

    __shared__ float tl[32][33];
    const int k0 = kx * 32, n0 = ny * 32;
    const int tx = threadIdx.x, ty = threadIdx.y;
#pragma unroll
    for (int dy = 0; dy < 32; dy += 8) {
        const int k = k0 + ty + dy, nn = n0 + tx;
        tl[ty + dy][tx] = (k < rows_in && nn < cols_in) ? src[(long)k * cols_in + nn] : 0.f;
    }
    __syncthreads();
#pragma unroll
    for (int dy = 0; dy < 32; dy += 8) {
        const int nn = n0 + ty + dy, k = k0 + tx;
        if (nn < cols_in && k < ldo) dst[(long)nn * ldo + k] = (__bf16)tl[tx][ty + dy];
    }
}

// ---------------------------------------------------------------------------
// Fused softmax, loops over all 8 heads per (i,b) block: relation/mask rows
// loaded ONCE. scores bf16, rows LDSC=640 wide ([512,640) = qr table).
// ---------------------------------------------------------------------------
__global__ __launch_bounds__(256) void softmax_rel(
    const __bf16* __restrict__ scores,
    const int* __restrict__ relation, const int* __restrict__ mask,
    __bf16* __restrict__ attn, __bf16* __restrict__ attnR,
    float* __restrict__ loss_part, const int* __restrict__ sep_p)
{
    const int i = blockIdx.x, b = blockIdx.y;
    const int t = threadIdx.x;
    const int* rrow = relation + ((long)b * NS + i) * NS;
    const int* mrow = mask + ((long)b * NS + i) * NS;
    const int r0 = rrow[t], r1 = rrow[t + 256];
    const int m0 = mrow[t], m1 = mrow[t + 256];
    const int sep = *sep_p;
    const int lane = t & 63, wv = t >> 6;

    __shared__ float qrl[RPAD];
    __shared__ float bins[RPAD];
    __shared__ float red[4];

    const float sc = 0.088388347648318447f;  // 1/sqrt(128)
    float lsum = 0.f;

#pragma unroll 1
    for (int h = 0; h < NH; ++h) {
        const long bh = (long)(b * NH + h);
        const __bf16* srow = scores + (bh * NS + i) * LDSC;
        __bf16* arow = attn + (bh * NS + i) * NS;
        __bf16* aRrow = attnR + (bh * NS + i) * RPAD;

        if (t < RPAD) { qrl[t] = (float)srow[NS + t]; bins[t] = 0.f; }
        __syncthreads();

        float v0 = ((float)srow[t] + qrl[r0]) * sc;
        float v1 = ((float)srow[t + 256] + qrl[r1]) * sc;
        if (m0 == 0) v0 = -1e9f;
        if (m1 == 0) v1 = -1e9f;

        float mx = fmaxf(v0, v1);
#pragma unroll
        for (int o = 32; o > 0; o >>= 1) mx = fmaxf(mx, __shfl_xor(mx, o, 64));
        if (lane == 0) red[wv] = mx;
        __syncthreads();
        mx = fmaxf(fmaxf(red[0], red[1]), fmaxf(red[2], red[3]));
        __syncthreads();

        const float e0 = __expf(v0 - mx), e1 = __expf(v1 - mx);
        float sm = e0 + e1;
#pragma unroll
        for (int o = 32; o > 0; o >>= 1) sm += __shfl_xor(sm, o, 64);
        if (lane == 0) red[wv] = sm;
        __syncthreads();
        sm = red[0] + red[1] + red[2] + red[3];

        const float inv = 1.f / sm;
        const float a0 = e0 * inv, a1 = e1 * inv;
        arow[t] = (__bf16)a0;
        arow[t + 256] = (__bf16)a1;
        atomicAdd(&bins[r0], a0);
        atomicAdd(&bins[r1], a1);
        if (t < sep) lsum += a0;
        if (t + 256 < sep) lsum += a1;
        __syncthreads();
        if (t < RPAD) aRrow[t] = (__bf16)bins[t];
        __syncthreads();
    }

#pragma unroll
    for (int o = 32; o > 0; o >>= 1) lsum += __shfl_xor(lsum, o, 64);
    if (lane == 0) red[wv] = lsum;
    __syncthreads();
    if (t == 0) loss_part[(long)b * NS + i] = red[0] + red[1] + red[2] + red[3];
}

// Wo split-K(2) reduce + residual + bias, fused LN2 -> out fp32 + h2 bf16.
__global__ __launch_bounds__(256) void wo_reduce_ln(
    const float* __restrict__ P, const float* __restrict__ x,
    const float* __restrict__ bo, const float* __restrict__ g,
    const float* __restrict__ bb, float* __restrict__ out,
    __bf16* __restrict__ h2)
{
    const int row = blockIdx.x;
    const int t = threadIdx.x;
    const long i4 = (long)row * 256 + t;
    const long sP = (long)BSROWS * ND / 4;
    const float4* P4 = (const float4*)P;
    float4 s = P4[i4];
    const float4 t1 = P4[i4 + sP];
    s.x += t1.x; s.y += t1.y; s.z += t1.z; s.w += t1.w;
    const int col = t * 4;
    const float4 xv = ((const float4*)x)[i4];
    const float4 bv = *(const float4*)&bo[col];
    float4 o;
    o.x = s.x + xv.x + bv.x; o.y = s.y + xv.y + bv.y;
    o.z = s.z + xv.z + bv.z; o.w = s.w + xv.w + bv.w;
    ((float4*)out)[i4] = o;

    float sum = o.x + o.y + o.z + o.w;
    float sum2 = o.x * o.x + o.y * o.y + o.z * o.z + o.w * o.w;
#pragma unroll
    for (int of = 32; of > 0; of >>= 1) {
        sum += __shfl_xor(sum, of, 64);
        sum2 += __shfl_xor(sum2, of, 64);
    }
    __shared__ float red[8];
    const int lane = t & 63, wv = t >> 6;
    if (lane == 0) { red[wv] = sum; red[4 + wv] = sum2; }
    __syncthreads();
    sum = red[0] + red[1] + red[2] + red[3];
    sum2 = red[4] + red[5] + red[6] + red[7];
    const float mean = sum * (1.f / ND);
    const float var = sum2 * (1.f / ND) - mean * mean;
    const float rs = rsqrtf(var + 1e-5f);
    const float ov[4] = {o.x, o.y, o.z, o.w};
    bf16x4 hb;
#pragma unroll
    for (int j = 0; j < 4; ++j)
        hb[j] = (__bf16)((ov[j] - mean) * rs * g[col + j] + bb[col + j]);
    *(bf16x4*)&h2[(long)row * ND + col] = hb;
}

// FFN2 split-K(2) reduce: out += b2 + sum_2 partials. Block 0 also finalizes loss.
__global__ __launch_bounds__(256) void ffn2_reduce(
    const float* __restrict__ P, const float* __restrict__ b2, float* __restrict__ out,
    const float* __restrict__ loss_part, const float* __restrict__ hist,
    const int* __restrict__ sep_p, float* __restrict__ out_loss)
{
    const int i4 = blockIdx.x * 256 + threadIdx.x;
    const long sP = (long)BSROWS * ND / 4;
    const float4* P4 = (const float4*)P;
    float4 s = P4[i4];
    const float4 t1 = P4[i4 + sP];
    s.x += t1.x; s.y += t1.y; s.z += t1.z; s.w += t1.w;
    const int col = (i4 * 4) & (ND - 1);
    const float4 bv = *(const float4*)&b2[col];
    float4 o = ((float4*)out)[i4];
    o.x += s.x + bv.x; o.y += s.y + bv.y;
    o.z += s.z + bv.z; o.w += s.w + bv.w;
    ((float4*)out)[i4] = o;

    if (blockIdx.x == 0) {
        const int t = threadIdx.x;
        const float4 v = ((const float4*)loss_part)[t];   // 1024 floats total
        float ls = v.x + v.y + v.z + v.w;
#pragma unroll
        for (int of = 32; of > 0; of >>= 1) ls += __shfl_xor(ls, of, 64);
        __shared__ float red[4];
        if ((t & 63) == 0) red[t >> 6] = ls;
        __syncthreads();
        if (t == 0) {
            const int sep = *sep_p;
            const float total = red[0] + red[1] + red[2] + red[3];
            const float denom = (float)NB * NH * NS * (float)(sep > 0 ? sep : 1);
            out_loss[0] = (sep > 0) ? hist[0] * total / denom : 0.f;
        }
    }
}

// ---------------------------------------------------------------------------
static inline int cdiv(int a, int b) { return (a + b - 1) / b; }

extern "C" void kernel_launch(void* const* d_in, const int* in_sizes, int n_in,
                              void* d_out, int out_size, void* d_ws, size_t ws_size,
                              hipStream_t stream)
{
    const float* x      = (const float*)d_in[0];
    const int* relation = (const int*)d_in[1];
    const int* mask     = (const int*)d_in[2];
    const int* sep_p    = (const int*)d_in[3];
    const float* hist   = (const float*)d_in[4];
    const float* Wq = (const float*)d_in[5],  *bq = (const float*)d_in[6];
    const float* Wk = (const float*)d_in[7],  *bk = (const float*)d_in[8];
    const float* Wv = (const float*)d_in[9],  *bv = (const float*)d_in[10];
    const float* Wo = (const float*)d_in[11], *bo = (const float*)d_in[12];
    const float* relk = (const float*)d_in[13];
    const float* relv = (const float*)d_in[14];
    const float* ln1g = (const float*)d_in[15], *ln1b = (const float*)d_in[16];
    const float* ln2g = (const float*)d_in[17], *ln2b = (const float*)d_in[18];
    const float* W1 = (const float*)d_in[19], *b1 = (const float*)d_in[20];
    const float* W2 = (const float*)d_in[21], *b2 = (const float*)d_in[22];
    const int R = in_sizes[13] / NDK;  // 51

    float* out = (float*)d_out;
    float* out_loss = out + (long)BSROWS * ND;

    char* p = (char*)d_ws;
    auto alloc = [&](size_t bytes) -> void* {
        void* r = (void*)p;
        p += (bytes + 255) & ~(size_t)255;
        return r;
    };
    __bf16* WqkvT   = (__bf16*)alloc((size_t)3 * ND * ND * 2);
    __bf16* WoT     = (__bf16*)alloc((size_t)ND * ND * 2);
    __bf16* W1T     = (__bf16*)alloc((size_t)NDFF * ND * 2);
    __bf16* W2T     = (__bf16*)alloc((size_t)ND * NDFF * 2);
    __bf16* relkT   = (__bf16*)alloc((size_t)128 * NDK * 2);
    __bf16* relvT   = (__bf16*)alloc((size_t)NDK * RPAD * 2);
    float*  biasqkv = (float*)alloc((size_t)3 * ND * 4);
    __bf16* h1      = (__bf16*)alloc((size_t)BSROWS * ND * 2);
    __bf16* qkvb    = (__bf16*)alloc((size_t)BSROWS * 3 * ND * 2);
    __bf16* vt      = (__bf16*)alloc((size_t)NBH * NDK * NS * 2);
    __bf16* attnb   = (__bf16*)alloc((size_t)NBH * NS * NS * 2);
    __bf16* attnR   = (__bf16*)alloc((size_t)NBH * NS * RPAD * 2);
    __bf16* ctxm    = (__bf16*)alloc((size_t)BSROWS * ND * 2);
    __bf16* h2      = (__bf16*)alloc((size_t)BSROWS * ND * 2);
    __bf16* F1      = (__bf16*)alloc((size_t)BSROWS * NDFF * 2);
    float*  loss_part = (float*)alloc((size_t)NB * NS * 4);
    float*  arena   = (float*)alloc((size_t)64 * 1024 * 1024);
    // arena aliasing (lifetimes disjoint):
    __bf16* scoresb = (__bf16*)arena;                   // 10.5MB, dead after softmax
    float* woPart   = arena;                            // [0,8)MB
    float* f2Part   = arena + (size_t)2 * 1024 * 1024;  // [8,16)MB

    const dim3 tb(32, 8);
    // fused weight prep + LN1 (13396 blocks)
    prep_weights<<<13396, tb, 0, stream>>>(Wq, Wk, Wv, Wo, W1, W2, relv,
                                           bq, bk, bv, relk, x, ln1g, ln1b,
                                           WqkvT, WoT, W1T, W2T, relvT,
                                           biasqkv, relkT, h1, R);

    // QKV: [1024,1024] @ [3072,1024]^T -> qkvb bf16 + fused V-transpose -> vt
    // (768 blocks, nt=16)
    gemm64<<<dim3(48, 16, 1), 256, 0, stream>>>(
        h1, WqkvT, nullptr, vt, nullptr, nullptr, nullptr,
        nullptr, qkvb, biasqkv,
        ND, ND, ND, 3 * ND,
        0, 0, 1, 0, 0, 1, 0, 1, 0, 8);

    // scores+qr fused: per-head q @ [k^T | relk^T] -> scoresb bf16 [512,640]
    // (1280 blocks, nt=2)
    gemm64<<<dim3(10, 8, NBH), 256, 0, stream>>>(
        qkvb, qkvb + ND, relkT, nullptr, nullptr, nullptr, nullptr,
        nullptr, scoresb, nullptr,
        NDK, 3 * ND, 3 * ND, LDSC,
        (long)NS * 3 * ND, NDK, NH,
        (long)NS * 3 * ND, NDK, NH,
        (long)NS * LDSC, 1, 0, 4);

    softmax_rel<<<dim3(NS, NB), 256, 0, stream>>>(
        scoresb, relation, mask, attnb, attnR, loss_part, sep_p);

    // ctx = attn @ v + attnR @ rel_v (fused epilogue) -> ctxm (merged heads)
    // 256 blocks, nt=8, no split
    gemm64<<<dim3(2, 8, NBH), 256, 0, stream>>>(
        attnb, vt, nullptr, nullptr, attnR, relvT, ctxm,
        nullptr, nullptr, nullptr,
        NS, NS, NS, NDK,
        (long)NS * NS, 0, 1,
        (long)NDK * NS, 0, 1,
        0, 1, 0, 16);

    // attn_out partials: ctxm @ Wo, split-K x2 (Ksp=512, nt=8), 512 blocks
    gemm64<<<dim3(16, 16, 2), 256, 0, stream>>>(
        ctxm, WoT, nullptr, nullptr, nullptr, nullptr, nullptr,
        woPart, nullptr, nullptr,
        512, ND, ND, ND,
        0, 0, 1, 0, 0, 1,
        0, 2, (long)BSROWS * ND, 0);

    // fused: out = x + bo + sum_2 partials; h2 = LN2(out)
    wo_reduce_ln<<<BSROWS, 256, 0, stream>>>(woPart, x, bo, ln2g, ln2b, out, h2);

    // FFN1: relu(h2 @ W1 + b1) -> F1 bf16 (1024 blocks, nt=16)
    gemm64<<<dim3(64, 16, 1), 256, 0, stream>>>(
        h2, W1T, nullptr, nullptr, nullptr, nullptr, nullptr,
        nullptr, F1, b1,
        ND, ND, ND, NDFF,
        0, 0, 1, 0, 0, 1, 0, 1, 0, 1);

    // FFN2 partials: F1 @ W2, split-K x2 (Ksp=2048, nt=32), 512 blocks
    gemm64<<<dim3(16, 16, 2), 256, 0, stream>>>(
        F1, W2T, nullptr, nullptr, nullptr, nullptr, nullptr,
        f2Part, nullptr, nullptr,
        2048, NDFF, NDFF, ND,
        0, 0, 1, 0, 0, 1,
        0, 2, (long)BSROWS * ND, 0);

    // FFN2 reduce + fused loss finalize
    ffn2_reduce<<<1024, 256, 0, stream>>>(f2Part, b2, out,
                                          loss_part, hist, sep_p, out_loss);
}

// Round 12
// 131.335 us; speedup vs baseline: 1.3162x; 1.2119x over previous
//
#include <hip/hip_runtime.h>
#include <hip/hip_bf16.h>

#define NB 2
#define NS 512
#define ND 1024
#define NH 8
#define NDK 128
#define NDFF 4096
#define RPAD 64
#define BSROWS 1024           /* B*S */
#define NBH 16                /* B*H */
#define QT 16                 /* q rows per attn block */
#define SLP 524               /* padded score-strip stride (floats) */

typedef __bf16 bf16x8 __attribute__((ext_vector_type(8)));
typedef __bf16 bf16x4 __attribute__((ext_vector_type(4)));
typedef float f32x4 __attribute__((ext_vector_type(4)));

#define BM 64
#define BN 64
#define BK 64

__device__ __forceinline__ void gload16(const void* g, void* l) {
    __builtin_amdgcn_global_load_lds(
        (const __attribute__((address_space(1))) void*)g,
        (__attribute__((address_space(3))) void*)l, 16, 0, 0);
}

// ---------------------------------------------------------------------------
// Counted-vmcnt pipelined MFMA GEMM, 64x64 tile, BK=64, 4 waves (R9-proven).
// flags: 1=relu, 8=QKV mode (col tiles >= 2048 write transposed V to vt).
// ---------------------------------------------------------------------------
__global__ __launch_bounds__(256, 4) void gemm64(
    const __bf16* __restrict__ A, const __bf16* __restrict__ Bt,
    __bf16* __restrict__ vt,
    float* __restrict__ Cf, __bf16* __restrict__ Cb,
    const float* __restrict__ bias,
    int Ksp, int lda, int ldb, int ldc,
    long sA, long sA2, int zdivA,
    long sB, long sB2, int zdivB,
    long sC, int nsplit, long sPart, int flags)
{
    __shared__ __bf16 As0[BM * BK];
    __shared__ __bf16 As1[BM * BK];
    __shared__ __bf16 Bs0[BN * BK];
    __shared__ __bf16 Bs1[BN * BK];

    // T1: XCD-bijective remap of the linear workgroup id (m204 formula).
    const unsigned gx = gridDim.x, gy = gridDim.y;
    const unsigned n = gx * gy * gridDim.z;
    const unsigned o = blockIdx.x + gx * (blockIdx.y + gy * blockIdx.z);
    const unsigned q = n >> 3, r = n & 7, xcd = o & 7;
    const unsigned nl = (xcd < r ? xcd * (q + 1) : r * (q + 1) + (xcd - r) * q) + (o >> 3);
    const unsigned bx = nl % gx, tmp = nl / gx;
    const unsigned by = tmp % gy, bz = tmp / gy;

    const int z = bz;
    const int bh = z / nsplit, sp = z - bh * nsplit;
    const long kbase = (long)sp * Ksp;
    A  += (long)(bh / zdivA) * sA + (long)(bh % zdivA) * sA2 + kbase;
    Bt += (long)(bh / zdivB) * sB + (long)(bh % zdivB) * sB2 + kbase;
    const long cbase = (long)bh * sC + (long)sp * sPart;

    const int tM = by * BM, tN = bx * BN;
    const int t = threadIdx.x, lane = t & 63, w = t >> 6;
    const int wr = w >> 1, wc = w & 1;

    const int srow = lane >> 3;
    const int scolE = ((((lane & 7) << 4) ^ (srow << 4)) >> 1);

    const __bf16* gA = A + (long)(tM + srow) * lda + scolE;
    const __bf16* gB = Bt + (long)(tN + srow) * ldb + scolE;

    f32x4 acc[2][2];
#pragma unroll
    for (int m = 0; m < 2; ++m)
#pragma unroll
        for (int nn = 0; nn < 2; ++nn)
#pragma unroll
            for (int j = 0; j < 4; ++j) acc[m][nn][j] = 0.f;

    const int r16 = lane & 15;
    const int kq = (lane >> 4) * 8;
    const int xorE = (r16 & 7) * 8;
    const int nt = Ksp / BK;

    auto STAGE = [&](__bf16* as, __bf16* bs, int k0) {
#pragma unroll
        for (int i = 0; i < 2; ++i) {
            const int rr = (w + i * 4) * 8;
            gload16(gA + (long)rr * lda + k0, (void*)&as[rr * BK]);
            gload16(gB + (long)rr * ldb + k0, (void*)&bs[rr * BK]);
        }
    };
    auto COMPUTE = [&](const __bf16* as, const __bf16* bs) {
        __builtin_amdgcn_s_setprio(1);
#pragma unroll
        for (int ks = 0; ks < 2; ++ks) {
            bf16x8 af[2], bv[2];
#pragma unroll
            for (int m = 0; m < 2; ++m)
                af[m] = *(const bf16x8*)&as[(wr * 32 + m * 16 + r16) * BK + ((ks * 32 + kq) ^ xorE)];
#pragma unroll
            for (int nn = 0; nn < 2; ++nn)
                bv[nn] = *(const bf16x8*)&bs[(wc * 32 + nn * 16 + r16) * BK + ((ks * 32 + kq) ^ xorE)];
#pragma unroll
            for (int m = 0; m < 2; ++m)
#pragma unroll
                for (int nn = 0; nn < 2; ++nn)
                    acc[m][nn] = __builtin_amdgcn_mfma_f32_16x16x32_bf16(af[m], bv[nn], acc[m][nn], 0, 0, 0);
        }
        __builtin_amdgcn_s_setprio(0);
    };

    STAGE(As0, Bs0, 0);
    STAGE(As1, Bs1, BK);
    for (int tt = 0; tt < nt; tt += 2) {
        asm volatile("s_waitcnt vmcnt(4)\n\ts_barrier" ::: "memory");
        COMPUTE(As0, Bs0);
        asm volatile("s_waitcnt lgkmcnt(0)\n\ts_barrier" ::: "memory");
        const bool more = (tt + 2 < nt);
        if (more) {
            STAGE(As0, Bs0, (tt + 2) * BK);
            asm volatile("s_waitcnt vmcnt(4)\n\ts_barrier" ::: "memory");
        } else {
            asm volatile("s_waitcnt vmcnt(0)\n\ts_barrier" ::: "memory");
        }
        COMPUTE(As1, Bs1);
        asm volatile("s_waitcnt lgkmcnt(0)\n\ts_barrier" ::: "memory");
        if (more) STAGE(As1, Bs1, (tt + 3) * BK);
    }

    const bool relu = (flags & 1) != 0;
    const bool vmode = (flags & 8) && (tN >= 2 * ND);
#pragma unroll
    for (int m = 0; m < 2; ++m) {
        const int gr0 = tM + wr * 32 + m * 16 + (lane >> 4) * 4;
#pragma unroll
        for (int nn = 0; nn < 2; ++nn) {
            const int gc = tN + wc * 32 + nn * 16 + (lane & 15);
            const float bb = bias ? bias[gc] : 0.f;
            if (vmode) {
                const int hd = gc - 2 * ND;
                const int b = gr0 >> 9, i = gr0 & 511;
                bf16x4 ov;
#pragma unroll
                for (int j = 0; j < 4; ++j) ov[j] = (__bf16)(acc[m][nn][j] + bb);
                *(bf16x4*)&vt[(((long)b * NH + (hd >> 7)) * NDK + (hd & 127)) * NS + i] = ov;
            } else {
#pragma unroll
                for (int j = 0; j < 4; ++j) {
                    float v = acc[m][nn][j] + bb;
                    if (relu) v = fmaxf(v, 0.f);
                    const long idx = cbase + (long)(gr0 + j) * ldc + gc;
                    if (Cb) Cb[idx] = (__bf16)v;
                    else Cf[idx] = v;
                }
            }
        }
    }
}

// ---------------------------------------------------------------------------
// Fused attention: scores (+rel bias, mask) -> softmax -> bins/loss -> PV
// (+ bins@rel_v) -> merged-head ctxm. Block = (qt, bh): 16 q-rows, 4 waves.
// ---------------------------------------------------------------------------
__global__ __launch_bounds__(256, 2) void attn_fused(
    const __bf16* __restrict__ qkvb, const __bf16* __restrict__ vt,
    const __bf16* __restrict__ relkT, const __bf16* __restrict__ relvT,
    const int* __restrict__ relation, const int* __restrict__ mask,
    __bf16* __restrict__ ctxm, float* __restrict__ loss_part,
    const int* __restrict__ sep_p)
{
    __shared__ float Sl[QT * SLP];          // 33.5 KB score strip (fp32)
    __shared__ __bf16 Ks0[64 * NDK];        // 16 KB
    __shared__ __bf16 Ks1[64 * NDK];        // 16 KB
    __shared__ float qrl[QT][RPAD];         // 4 KB
    __shared__ float bins[QT][68];          // 4.25 KB
    __shared__ float redl[4];

    // XCD-locality remap: same-bh blocks contiguous per XCD (512 % 8 == 0)
    const unsigned o = blockIdx.x + 32u * blockIdx.y;
    const unsigned nl = (o & 7) * 64u + (o >> 3);
    const int qt = nl & 31, bh = nl >> 5;
    const int b = bh >> 3, h = bh & 7;
    const int i0 = qt * QT;

    const int t = threadIdx.x, lane = t & 63, w = t >> 6;
    const int r16 = lane & 15;
    const int kq = (lane >> 4) * 8;
    const int xorE = (r16 & 7) * 8;
    const int sep = *sep_p;

    // --- Q fragments (registers; shared by QK^T and qr)
    bf16x8 qf[4];
    {
        const __bf16* qrow = qkvb + ((long)(b * NS + i0 + r16)) * (3 * ND) + h * NDK;
#pragma unroll
        for (int ks = 0; ks < 4; ++ks)
            qf[ks] = *(const bf16x8*)(qrow + ks * 32 + kq);
    }

    // --- qr table: Q(16x128) @ relkT(64x128)^T -> qrl[16][64]
    {
        f32x4 a;
#pragma unroll
        for (int j = 0; j < 4; ++j) a[j] = 0.f;
#pragma unroll
        for (int ks = 0; ks < 4; ++ks) {
            const bf16x8 bfr = *(const bf16x8*)(relkT + (long)(w * 16 + r16) * NDK + ks * 32 + kq);
            a = __builtin_amdgcn_mfma_f32_16x16x32_bf16(qf[ks], bfr, a, 0, 0, 0);
        }
#pragma unroll
        for (int j = 0; j < 4; ++j)
            qrl[(lane >> 4) * 4 + j][w * 16 + (lane & 15)] = a[j];
    }
    for (int idx = t; idx < QT * 68; idx += 256) ((float*)bins)[idx] = 0.f;

    // --- scores: K-tiles of 64, counted-vmcnt dual buffer
    auto KSTAGE = [&](__bf16* ksb, int kv0) {
#pragma unroll
        for (int ii = 0; ii < 4; ++ii) {
            const int Lc = (w * 4 + ii) * 64 + lane;
            const int j = Lc >> 4, cc = Lc & 15;
            gload16(qkvb + ((long)(b * NS + kv0 + j)) * (3 * ND) + ND + h * NDK + ((cc ^ (j & 7)) << 3),
                    (void*)&ksb[(w * 4 + ii) * 512]);
        }
    };
    auto SCOMP = [&](const __bf16* ksb, int kv0) {
        f32x4 s;
#pragma unroll
        for (int j = 0; j < 4; ++j) s[j] = 0.f;
#pragma unroll
        for (int ks = 0; ks < 4; ++ks) {
            const bf16x8 bfr = *(const bf16x8*)&ksb[(w * 16 + r16) * NDK + ((ks * 32 + kq) ^ xorE)];
            s = __builtin_amdgcn_mfma_f32_16x16x32_bf16(qf[ks], bfr, s, 0, 0, 0);
        }
        const int colb = kv0 + w * 16 + (lane & 15);
#pragma unroll
        for (int j = 0; j < 4; ++j)
            Sl[((lane >> 4) * 4 + j) * SLP + colb] = s[j];
    };

    KSTAGE(Ks0, 0);
    KSTAGE(Ks1, 64);
    for (int tt = 0; tt < 8; tt += 2) {
        asm volatile("s_waitcnt vmcnt(4)\n\ts_barrier" ::: "memory");
        SCOMP(Ks0, tt * 64);
        asm volatile("s_waitcnt lgkmcnt(0)\n\ts_barrier" ::: "memory");
        const bool more = (tt + 2 < 8);
        if (more) {
            KSTAGE(Ks0, (tt + 2) * 64);
            asm volatile("s_waitcnt vmcnt(4)\n\ts_barrier" ::: "memory");
        } else {
            asm volatile("s_waitcnt vmcnt(0)\n\ts_barrier" ::: "memory");
        }
        SCOMP(Ks1, (tt + 1) * 64);
        asm volatile("s_waitcnt lgkmcnt(0)\n\ts_barrier" ::: "memory");
        if (more) KSTAGE(Ks1, (tt + 3) * 64);
    }

    // --- softmax: wave w owns rows 4w..4w+3 (512 cols each)
    const float sc = 0.088388347648318447f;  // 1/sqrt(128)
    float lsum = 0.f;
#pragma unroll 1
    for (int rr = 0; rr < 4; ++rr) {
        const int row = w * 4 + rr;
        const int* relrow = relation + ((long)(b * NS + i0 + row)) * NS;
        const int* mrow = mask + ((long)(b * NS + i0 + row)) * NS;
        float v[8]; int rl[8];
        float mx = -1e30f;
#pragma unroll
        for (int c = 0; c < 8; ++c) {
            const int j = lane + c * 64;
            const float s = Sl[row * SLP + j];
            rl[c] = relrow[j];
            float vv = (s + qrl[row][rl[c]]) * sc;
            if (mrow[j] == 0) vv = -1e9f;
            v[c] = vv;
            mx = fmaxf(mx, vv);
        }
#pragma unroll
        for (int of = 32; of > 0; of >>= 1) mx = fmaxf(mx, __shfl_xor(mx, of, 64));
        float sm = 0.f;
#pragma unroll
        for (int c = 0; c < 8; ++c) { v[c] = __expf(v[c] - mx); sm += v[c]; }
#pragma unroll
        for (int of = 32; of > 0; of >>= 1) sm += __shfl_xor(sm, of, 64);
        const float inv = 1.f / sm;
#pragma unroll
        for (int c = 0; c < 8; ++c) {
            const float a = v[c] * inv;
            Sl[row * SLP + lane + c * 64] = a;
            atomicAdd(&bins[row][rl[c]], a);
            if (lane + c * 64 < sep) lsum += a;
        }
    }
#pragma unroll
    for (int of = 32; of > 0; of >>= 1) lsum += __shfl_xor(lsum, of, 64);
    if (lane == 0) redl[w] = lsum;
    __syncthreads();   // Sl/bins visible to all; loss partials in redl
    if (t == 0) loss_part[bh * 32 + qt] = redl[0] + redl[1] + redl[2] + redl[3];

    // --- PV: wave w owns O cols [w*32, w*32+32); A = attn rows from Sl
    f32x4 oacc[2];
#pragma unroll
    for (int nn = 0; nn < 2; ++nn)
#pragma unroll
        for (int j = 0; j < 4; ++j) oacc[nn][j] = 0.f;

#pragma unroll
    for (int kc = 0; kc < 16; ++kc) {
        const float4 a0 = *(const float4*)&Sl[r16 * SLP + kc * 32 + kq];
        const float4 a1 = *(const float4*)&Sl[r16 * SLP + kc * 32 + kq + 4];
        bf16x8 af;
        af[0] = (__bf16)a0.x; af[1] = (__bf16)a0.y; af[2] = (__bf16)a0.z; af[3] = (__bf16)a0.w;
        af[4] = (__bf16)a1.x; af[5] = (__bf16)a1.y; af[6] = (__bf16)a1.z; af[7] = (__bf16)a1.w;
#pragma unroll
        for (int nn = 0; nn < 2; ++nn) {
            const bf16x8 bfr = *(const bf16x8*)(vt + ((long)bh * NDK + w * 32 + nn * 16 + r16) * NS + kc * 32 + kq);
            oacc[nn] = __builtin_amdgcn_mfma_f32_16x16x32_bf16(af, bfr, oacc[nn], 0, 0, 0);
        }
    }
    // bins @ relvT fold (K = 64)
#pragma unroll
    for (int kc = 0; kc < 2; ++kc) {
        const float4 b0 = *(const float4*)&bins[r16][kc * 32 + kq];
        const float4 b1 = *(const float4*)&bins[r16][kc * 32 + kq + 4];
        bf16x8 af;
        af[0] = (__bf16)b0.x; af[1] = (__bf16)b0.y; af[2] = (__bf16)b0.z; af[3] = (__bf16)b0.w;
        af[4] = (__bf16)b1.x; af[5] = (__bf16)b1.y; af[6] = (__bf16)b1.z; af[7] = (__bf16)b1.w;
#pragma unroll
        for (int nn = 0; nn < 2; ++nn) {
            const bf16x8 bfr = *(const bf16x8*)(relvT + (long)(w * 32 + nn * 16 + r16) * RPAD + kc * 32 + kq);
            oacc[nn] = __builtin_amdgcn_mfma_f32_16x16x32_bf16(af, bfr, oacc[nn], 0, 0, 0);
        }
    }
#pragma unroll
    for (int nn = 0; nn < 2; ++nn)
#pragma unroll
        for (int j = 0; j < 4; ++j) {
            const int row = (lane >> 4) * 4 + j;
            ctxm[((long)(b * NS + i0 + row)) * ND + h * NDK + w * 32 + nn * 16 + (lane & 15)] =
                (__bf16)oacc[nn][j];
        }
}

// ---------------------------------------------------------------------------
// Fused prep: weight transposes + bias pack + relk pad + LN1 (13396 blocks).
// ---------------------------------------------------------------------------
__global__ void prep_weights(
    const float* __restrict__ Wq, const float* __restrict__ Wk,
    const float* __restrict__ Wv, const float* __restrict__ Wo,
    const float* __restrict__ W1, const float* __restrict__ W2,
    const float* __restrict__ relv,
    const float* __restrict__ bq, const float* __restrict__ bk,
    const float* __restrict__ bv, const float* __restrict__ relk,
    const float* __restrict__ x, const float* __restrict__ ln1g,
    const float* __restrict__ ln1b,
    __bf16* __restrict__ WqkvT, __bf16* __restrict__ WoT,
    __bf16* __restrict__ W1T, __bf16* __restrict__ W2T,
    __bf16* __restrict__ relvT, float* __restrict__ biasqkv,
    __bf16* __restrict__ relkT, __bf16* __restrict__ h1, int R)
{
    const int tile = blockIdx.x;
    const int t = threadIdx.y * 32 + threadIdx.x;

    if (tile >= 12372) {   // LN1 row
        const long row = tile - 12372;
        const float* xr = x + row * ND;
        float4 v = reinterpret_cast<const float4*>(xr)[t];
        float s = v.x + v.y + v.z + v.w;
        float s2 = v.x * v.x + v.y * v.y + v.z * v.z + v.w * v.w;
#pragma unroll
        for (int o = 32; o > 0; o >>= 1) {
            s += __shfl_xor(s, o, 64);
            s2 += __shfl_xor(s2, o, 64);
        }
        __shared__ float red[8];
        const int lane = t & 63, wv = t >> 6;
        if (lane == 0) { red[wv] = s; red[4 + wv] = s2; }
        __syncthreads();
        s = red[0] + red[1] + red[2] + red[3];
        s2 = red[4] + red[5] + red[6] + red[7];
        const float mean = s * (1.f / ND);
        const float var = s2 * (1.f / ND) - mean * mean;
        const float rs = rsqrtf(var + 1e-5f);
        const float xv[4] = {v.x, v.y, v.z, v.w};
        bf16x4 o;
#pragma unroll
        for (int j = 0; j < 4; ++j) {
            const int c = t * 4 + j;
            o[j] = (__bf16)((xv[j] - mean) * rs * ln1g[c] + ln1b[c]);
        }
        *(bf16x4*)&h1[row * ND + t * 4] = o;
        return;
    }
    if (tile >= 12296) {   // bias pack + relk pad (flat)
        const int ft = (tile - 12296) * 256 + t;
        if (ft < ND) biasqkv[ft] = bq[ft];
        else if (ft < 2 * ND) biasqkv[ft] = bk[ft - ND];
        else if (ft < 3 * ND) biasqkv[ft] = bv[ft - 2 * ND];
        else {
            const int idx = ft - 3 * ND;
            if (idx < 128 * NDK) {
                const int r = idx / NDK;
                relkT[idx] = (r < R) ? (__bf16)relk[idx] : (__bf16)0.f;
            }
        }
        return;
    }
    const float* src; __bf16* dst;
    int rows_in, cols_in, ldo, kx, ny;
    if (tile < 4096) {
        const int m = tile >> 10, r = tile & 1023;
        kx = r & 31; ny = r >> 5;
        rows_in = 1024; cols_in = 1024; ldo = 1024;
        src = m == 0 ? Wq : m == 1 ? Wk : m == 2 ? Wv : Wo;
        dst = m == 3 ? WoT : WqkvT + (size_t)m * 1024 * 1024;
    } else if (tile < 8192) {
        const int r = tile - 4096;
        kx = r & 31; ny = r >> 5;
        rows_in = 1024; cols_in = 4096; ldo = 1024; src = W1; dst = W1T;
    } else if (tile < 12288) {
        const int r = tile - 8192;
        kx = r & 127; ny = r >> 7;
        rows_in = 4096; cols_in = 1024; ldo = 4096; src = W2; dst = W2T;
    } else {
        const int r = tile - 12288;
        kx = r & 1; ny = r >> 1;
        rows_in = R; cols_in = 128; ldo = 64; src = relv; dst = relvT;
    }

    __shared__ float tl[32][33];
    const int k0 = kx * 32, n0 = ny * 32;
    const int tx = threadIdx.x, ty = threadIdx.y;
#pragma unroll
    for (int dy = 0; dy < 32; dy += 8) {
        const int k = k0 + ty + dy, nn = n0 + tx;
        tl[ty + dy][tx] = (k < rows_in && nn < cols_in) ? src[(long)k * cols_in + nn] : 0.f;
    }
    __syncthreads();
#pragma unroll
    for (int dy = 0; dy < 32; dy += 8) {
        const int nn = n0 + ty + dy, k = k0 + tx;
        if (nn < cols_in && k < ldo) dst[(long)nn * ldo + k] = (__bf16)tl[tx][ty + dy];
    }
}

// Wo split-K(2) reduce + residual + bias, fused LN2 -> out fp32 + h2 bf16.
__global__ __launch_bounds__(256) void wo_reduce_ln(
    const float* __restrict__ P, const float* __restrict__ x,
    const float* __restrict__ bo, const float* __restrict__ g,
    const float* __restrict__ bb, float* __restrict__ out,
    __bf16* __restrict__ h2)
{
    const int row = blockIdx.x;
    const int t = threadIdx.x;
    const long i4 = (long)row * 256 + t;
    const long sP = (long)BSROWS * ND / 4;
    const float4* P4 = (const float4*)P;
    float4 s = P4[i4];
    const float4 t1 = P4[i4 + sP];
    s.x += t1.x; s.y += t1.y; s.z += t1.z; s.w += t1.w;
    const int col = t * 4;
    const float4 xv = ((const float4*)x)[i4];
    const float4 bv = *(const float4*)&bo[col];
    float4 o;
    o.x = s.x + xv.x + bv.x; o.y = s.y + xv.y + bv.y;
    o.z = s.z + xv.z + bv.z; o.w = s.w + xv.w + bv.w;
    ((float4*)out)[i4] = o;

    float sum = o.x + o.y + o.z + o.w;
    float sum2 = o.x * o.x + o.y * o.y + o.z * o.z + o.w * o.w;
#pragma unroll
    for (int of = 32; of > 0; of >>= 1) {
        sum += __shfl_xor(sum, of, 64);
        sum2 += __shfl_xor(sum2, of, 64);
    }
    __shared__ float red[8];
    const int lane = t & 63, wv = t >> 6;
    if (lane == 0) { red[wv] = sum; red[4 + wv] = sum2; }
    __syncthreads();
    sum = red[0] + red[1] + red[2] + red[3];
    sum2 = red[4] + red[5] + red[6] + red[7];
    const float mean = sum * (1.f / ND);
    const float var = sum2 * (1.f / ND) - mean * mean;
    const float rs = rsqrtf(var + 1e-5f);
    const float ov[4] = {o.x, o.y, o.z, o.w};
    bf16x4 hb;
#pragma unroll
    for (int j = 0; j < 4; ++j)
        hb[j] = (__bf16)((ov[j] - mean) * rs * g[col + j] + bb[col + j]);
    *(bf16x4*)&h2[(long)row * ND + col] = hb;
}

// FFN2 split-K(2) reduce: out += b2 + sum_2 partials. Block 0 finalizes loss
// (512 per-block partials).
__global__ __launch_bounds__(256) void ffn2_reduce(
    const float* __restrict__ P, const float* __restrict__ b2, float* __restrict__ out,
    const float* __restrict__ loss_part, const float* __restrict__ hist,
    const int* __restrict__ sep_p, float* __restrict__ out_loss)
{
    const int i4 = blockIdx.x * 256 + threadIdx.x;
    const long sP = (long)BSROWS * ND / 4;
    const float4* P4 = (const float4*)P;
    float4 s = P4[i4];
    const float4 t1 = P4[i4 + sP];
    s.x += t1.x; s.y += t1.y; s.z += t1.z; s.w += t1.w;
    const int col = (i4 * 4) & (ND - 1);
    const float4 bv = *(const float4*)&b2[col];
    float4 o = ((float4*)out)[i4];
    o.x += s.x + bv.x; o.y += s.y + bv.y;
    o.z += s.z + bv.z; o.w += s.w + bv.w;
    ((float4*)out)[i4] = o;

    if (blockIdx.x == 0) {
        const int t = threadIdx.x;
        float ls = 0.f;
        if (t < 128) {
            const float4 v = ((const float4*)loss_part)[t];   // 512 floats
            ls = v.x + v.y + v.z + v.w;
        }
#pragma unroll
        for (int of = 32; of > 0; of >>= 1) ls += __shfl_xor(ls, of, 64);
        __shared__ float red[4];
        if ((t & 63) == 0) red[t >> 6] = ls;
        __syncthreads();
        if (t == 0) {
            const int sep = *sep_p;
            const float total = red[0] + red[1] + red[2] + red[3];
            const float denom = (float)NB * NH * NS * (float)(sep > 0 ? sep : 1);
            out_loss[0] = (sep > 0) ? hist[0] * total / denom : 0.f;
        }
    }
}

// ---------------------------------------------------------------------------
extern "C" void kernel_launch(void* const* d_in, const int* in_sizes, int n_in,
                              void* d_out, int out_size, void* d_ws, size_t ws_size,
                              hipStream_t stream)
{
    const float* x      = (const float*)d_in[0];
    const int* relation = (const int*)d_in[1];
    const int* mask     = (const int*)d_in[2];
    const int* sep_p    = (const int*)d_in[3];
    const float* hist   = (const float*)d_in[4];
    const float* Wq = (const float*)d_in[5],  *bq = (const float*)d_in[6];
    const float* Wk = (const float*)d_in[7],  *bk = (const float*)d_in[8];
    const float* Wv = (const float*)d_in[9],  *bv = (const float*)d_in[10];
    const float* Wo = (const float*)d_in[11], *bo = (const float*)d_in[12];
    const float* relk = (const float*)d_in[13];
    const float* relv = (const float*)d_in[14];
    const float* ln1g = (const float*)d_in[15], *ln1b = (const float*)d_in[16];
    const float* ln2g = (const float*)d_in[17], *ln2b = (const float*)d_in[18];
    const float* W1 = (const float*)d_in[19], *b1 = (const float*)d_in[20];
    const float* W2 = (const float*)d_in[21], *b2 = (const float*)d_in[22];
    const int R = in_sizes[13] / NDK;  // 51

    float* out = (float*)d_out;
    float* out_loss = out + (long)BSROWS * ND;

    char* p = (char*)d_ws;
    auto alloc = [&](size_t bytes) -> void* {
        void* r = (void*)p;
        p += (bytes + 255) & ~(size_t)255;
        return r;
    };
    __bf16* WqkvT   = (__bf16*)alloc((size_t)3 * ND * ND * 2);
    __bf16* WoT     = (__bf16*)alloc((size_t)ND * ND * 2);
    __bf16* W1T     = (__bf16*)alloc((size_t)NDFF * ND * 2);
    __bf16* W2T     = (__bf16*)alloc((size_t)ND * NDFF * 2);
    __bf16* relkT   = (__bf16*)alloc((size_t)128 * NDK * 2);
    __bf16* relvT   = (__bf16*)alloc((size_t)NDK * RPAD * 2);
    float*  biasqkv = (float*)alloc((size_t)3 * ND * 4);
    __bf16* h1      = (__bf16*)alloc((size_t)BSROWS * ND * 2);
    __bf16* qkvb    = (__bf16*)alloc((size_t)BSROWS * 3 * ND * 2);
    __bf16* vt      = (__bf16*)alloc((size_t)NBH * NDK * NS * 2);
    __bf16* ctxm    = (__bf16*)alloc((size_t)BSROWS * ND * 2);
    __bf16* h2      = (__bf16*)alloc((size_t)BSROWS * ND * 2);
    __bf16* F1      = (__bf16*)alloc((size_t)BSROWS * NDFF * 2);
    float*  loss_part = (float*)alloc((size_t)512 * 4);
    float*  arena   = (float*)alloc((size_t)16 * 1024 * 1024);
    float* woPart   = arena;                            // 8 MB
    float* f2Part   = arena + (size_t)2 * 1024 * 1024;  // 8 MB

    const dim3 tb(32, 8);
    prep_weights<<<13396, tb, 0, stream>>>(Wq, Wk, Wv, Wo, W1, W2, relv,
                                           bq, bk, bv, relk, x, ln1g, ln1b,
                                           WqkvT, WoT, W1T, W2T, relvT,
                                           biasqkv, relkT, h1, R);

    // QKV + fused V-transpose (768 blocks, nt=16)
    gemm64<<<dim3(48, 16, 1), 256, 0, stream>>>(
        h1, WqkvT, vt, nullptr, qkvb, biasqkv,
        ND, ND, ND, 3 * ND,
        0, 0, 1, 0, 0, 1, 0, 1, 0, 8);

    // fused attention middle (512 blocks)
    attn_fused<<<dim3(32, 16), 256, 0, stream>>>(
        qkvb, vt, relkT, relvT, relation, mask, ctxm, loss_part, sep_p);

    // attn_out partials: ctxm @ Wo, split-K x2 (Ksp=512, nt=8), 512 blocks
    gemm64<<<dim3(16, 16, 2), 256, 0, stream>>>(
        ctxm, WoT, nullptr, woPart, nullptr, nullptr,
        512, ND, ND, ND,
        0, 0, 1, 0, 0, 1,
        0, 2, (long)BSROWS * ND, 0);

    wo_reduce_ln<<<BSROWS, 256, 0, stream>>>(woPart, x, bo, ln2g, ln2b, out, h2);

    // FFN1: relu(h2 @ W1 + b1) -> F1 bf16 (1024 blocks, nt=16)
    gemm64<<<dim3(64, 16, 1), 256, 0, stream>>>(
        h2, W1T, nullptr, nullptr, F1, b1,
        ND, ND, ND, NDFF,
        0, 0, 1, 0, 0, 1, 0, 1, 0, 1);

    // FFN2 partials: F1 @ W2, split-K x2 (Ksp=2048, nt=32), 512 blocks
    gemm64<<<dim3(16, 16, 2), 256, 0, stream>>>(
        F1, W2T, nullptr, f2Part, nullptr, nullptr,
        2048, NDFF, NDFF, ND,
        0, 0, 1, 0, 0, 1,
        0, 2, (long)BSROWS * ND, 0);

    ffn2_reduce<<<1024, 256, 0, stream>>>(f2Part, b2, out,
                                          loss_part, hist, sep_p, out_loss);
}

// Round 13
// 131.281 us; speedup vs baseline: 1.3167x; 1.0004x over previous
//
#include <hip/hip_runtime.h>
#include <hip/hip_bf16.h>

#define NB 2
#define NS 512
#define ND 1024
#define NH 8
#define NDK 128
#define NDFF 4096
#define RPAD 64
#define BSROWS 1024           /* B*S */
#define NBH 16                /* B*H */
#define QT 16                 /* q rows per attn block */
#define SLB 536               /* padded score-strip stride (bf16 elems) */

typedef __bf16 bf16x8 __attribute__((ext_vector_type(8)));
typedef __bf16 bf16x4 __attribute__((ext_vector_type(4)));
typedef float f32x4 __attribute__((ext_vector_type(4)));

#define BM 64
#define BN 64
#define BK 64

__device__ __forceinline__ void gload16(const void* g, void* l) {
    __builtin_amdgcn_global_load_lds(
        (const __attribute__((address_space(1))) void*)g,
        (__attribute__((address_space(3))) void*)l, 16, 0, 0);
}

// ---------------------------------------------------------------------------
// Counted-vmcnt pipelined MFMA GEMM, 64x64 tile, BK=64, 4 waves (R9-proven).
// flags: 1=relu, 8=QKV mode (col tiles >= 2048 write transposed V to vt).
// ---------------------------------------------------------------------------
__global__ __launch_bounds__(256, 4) void gemm64(
    const __bf16* __restrict__ A, const __bf16* __restrict__ Bt,
    __bf16* __restrict__ vt,
    float* __restrict__ Cf, __bf16* __restrict__ Cb,
    const float* __restrict__ bias,
    int Ksp, int lda, int ldb, int ldc,
    long sA, long sA2, int zdivA,
    long sB, long sB2, int zdivB,
    long sC, int nsplit, long sPart, int flags)
{
    __shared__ __bf16 As0[BM * BK];
    __shared__ __bf16 As1[BM * BK];
    __shared__ __bf16 Bs0[BN * BK];
    __shared__ __bf16 Bs1[BN * BK];

    const unsigned gx = gridDim.x, gy = gridDim.y;
    const unsigned n = gx * gy * gridDim.z;
    const unsigned o = blockIdx.x + gx * (blockIdx.y + gy * blockIdx.z);
    const unsigned q = n >> 3, r = n & 7, xcd = o & 7;
    const unsigned nl = (xcd < r ? xcd * (q + 1) : r * (q + 1) + (xcd - r) * q) + (o >> 3);
    const unsigned bx = nl % gx, tmp = nl / gx;
    const unsigned by = tmp % gy, bz = tmp / gy;

    const int z = bz;
    const int bh = z / nsplit, sp = z - bh * nsplit;
    const long kbase = (long)sp * Ksp;
    A  += (long)(bh / zdivA) * sA + (long)(bh % zdivA) * sA2 + kbase;
    Bt += (long)(bh / zdivB) * sB + (long)(bh % zdivB) * sB2 + kbase;
    const long cbase = (long)bh * sC + (long)sp * sPart;

    const int tM = by * BM, tN = bx * BN;
    const int t = threadIdx.x, lane = t & 63, w = t >> 6;
    const int wr = w >> 1, wc = w & 1;

    const int srow = lane >> 3;
    const int scolE = ((((lane & 7) << 4) ^ (srow << 4)) >> 1);

    const __bf16* gA = A + (long)(tM + srow) * lda + scolE;
    const __bf16* gB = Bt + (long)(tN + srow) * ldb + scolE;

    f32x4 acc[2][2];
#pragma unroll
    for (int m = 0; m < 2; ++m)
#pragma unroll
        for (int nn = 0; nn < 2; ++nn)
#pragma unroll
            for (int j = 0; j < 4; ++j) acc[m][nn][j] = 0.f;

    const int r16 = lane & 15;
    const int kq = (lane >> 4) * 8;
    const int xorE = (r16 & 7) * 8;
    const int nt = Ksp / BK;

    auto STAGE = [&](__bf16* as, __bf16* bs, int k0) {
#pragma unroll
        for (int i = 0; i < 2; ++i) {
            const int rr = (w + i * 4) * 8;
            gload16(gA + (long)rr * lda + k0, (void*)&as[rr * BK]);
            gload16(gB + (long)rr * ldb + k0, (void*)&bs[rr * BK]);
        }
    };
    auto COMPUTE = [&](const __bf16* as, const __bf16* bs) {
        __builtin_amdgcn_s_setprio(1);
#pragma unroll
        for (int ks = 0; ks < 2; ++ks) {
            bf16x8 af[2], bv[2];
#pragma unroll
            for (int m = 0; m < 2; ++m)
                af[m] = *(const bf16x8*)&as[(wr * 32 + m * 16 + r16) * BK + ((ks * 32 + kq) ^ xorE)];
#pragma unroll
            for (int nn = 0; nn < 2; ++nn)
                bv[nn] = *(const bf16x8*)&bs[(wc * 32 + nn * 16 + r16) * BK + ((ks * 32 + kq) ^ xorE)];
#pragma unroll
            for (int m = 0; m < 2; ++m)
#pragma unroll
                for (int nn = 0; nn < 2; ++nn)
                    acc[m][nn] = __builtin_amdgcn_mfma_f32_16x16x32_bf16(af[m], bv[nn], acc[m][nn], 0, 0, 0);
        }
        __builtin_amdgcn_s_setprio(0);
    };

    STAGE(As0, Bs0, 0);
    STAGE(As1, Bs1, BK);
    for (int tt = 0; tt < nt; tt += 2) {
        asm volatile("s_waitcnt vmcnt(4)\n\ts_barrier" ::: "memory");
        COMPUTE(As0, Bs0);
        asm volatile("s_waitcnt lgkmcnt(0)\n\ts_barrier" ::: "memory");
        const bool more = (tt + 2 < nt);
        if (more) {
            STAGE(As0, Bs0, (tt + 2) * BK);
            asm volatile("s_waitcnt vmcnt(4)\n\ts_barrier" ::: "memory");
        } else {
            asm volatile("s_waitcnt vmcnt(0)\n\ts_barrier" ::: "memory");
        }
        COMPUTE(As1, Bs1);
        asm volatile("s_waitcnt lgkmcnt(0)\n\ts_barrier" ::: "memory");
        if (more) STAGE(As1, Bs1, (tt + 3) * BK);
    }

    const bool relu = (flags & 1) != 0;
    const bool vmode = (flags & 8) && (tN >= 2 * ND);
#pragma unroll
    for (int m = 0; m < 2; ++m) {
        const int gr0 = tM + wr * 32 + m * 16 + (lane >> 4) * 4;
#pragma unroll
        for (int nn = 0; nn < 2; ++nn) {
            const int gc = tN + wc * 32 + nn * 16 + (lane & 15);
            const float bb = bias ? bias[gc] : 0.f;
            if (vmode) {
                const int hd = gc - 2 * ND;
                const int b = gr0 >> 9, i = gr0 & 511;
                bf16x4 ov;
#pragma unroll
                for (int j = 0; j < 4; ++j) ov[j] = (__bf16)(acc[m][nn][j] + bb);
                *(bf16x4*)&vt[(((long)b * NH + (hd >> 7)) * NDK + (hd & 127)) * NS + i] = ov;
            } else {
#pragma unroll
                for (int j = 0; j < 4; ++j) {
                    float v = acc[m][nn][j] + bb;
                    if (relu) v = fmaxf(v, 0.f);
                    const long idx = cbase + (long)(gr0 + j) * ldc + gc;
                    if (Cb) Cb[idx] = (__bf16)v;
                    else Cf[idx] = v;
                }
            }
        }
    }
}

// ---------------------------------------------------------------------------
// Fused attention v2: scores (LDS K dual-buf) -> softmax (batched rel/mask)
// -> PV (LDS V dual-buf, prefetched under softmax) + bins@rel_v -> ctxm.
// Block = (qt, bh): 16 q-rows, 4 waves, ~58 KB LDS, 2 blocks/CU.
// ---------------------------------------------------------------------------
__global__ __launch_bounds__(256, 2) void attn_fused(
    const __bf16* __restrict__ qkvb, const __bf16* __restrict__ vt,
    const __bf16* __restrict__ relkT, const __bf16* __restrict__ relvT,
    const int* __restrict__ relation, const int* __restrict__ mask,
    __bf16* __restrict__ ctxm, float* __restrict__ loss_part,
    const int* __restrict__ sep_p)
{
    __shared__ __bf16 Sl[QT * SLB];         // 16.75 KB score/attn strip (bf16)
    __shared__ __bf16 Ks0[64 * NDK];        // 16 KB (K tiles, reused as V tiles)
    __shared__ __bf16 Ks1[64 * NDK];        // 16 KB
    __shared__ float qrl[QT][RPAD];         // 4 KB
    __shared__ float bins[QT][68];          // 4.25 KB
    __shared__ float redl[4];

    const unsigned o = blockIdx.x + 32u * blockIdx.y;
    const unsigned nl = (o & 7) * 64u + (o >> 3);
    const int qt = nl & 31, bh = nl >> 5;
    const int b = bh >> 3, h = bh & 7;
    const int i0 = qt * QT;

    const int t = threadIdx.x, lane = t & 63, w = t >> 6;
    const int r16 = lane & 15;
    const int kq = (lane >> 4) * 8;
    const int xorE = (r16 & 7) * 8;
    const int sep = *sep_p;

    // --- Q fragments
    bf16x8 qf[4];
    {
        const __bf16* qrow = qkvb + ((long)(b * NS + i0 + r16)) * (3 * ND) + h * NDK;
#pragma unroll
        for (int ks = 0; ks < 4; ++ks)
            qf[ks] = *(const bf16x8*)(qrow + ks * 32 + kq);
    }

    // --- batched rel/mask loads (lane owns 8 consecutive j; wave w owns rows 4w..4w+3)
    int4 ra[4][2], ma[4][2];
#pragma unroll
    for (int rr = 0; rr < 4; ++rr) {
        const long rg = (long)(b * NS + i0 + w * 4 + rr) * NS;
        ra[rr][0] = ((const int4*)(relation + rg))[lane * 2];
        ra[rr][1] = ((const int4*)(relation + rg))[lane * 2 + 1];
        ma[rr][0] = ((const int4*)(mask + rg))[lane * 2];
        ma[rr][1] = ((const int4*)(mask + rg))[lane * 2 + 1];
    }

    // --- qr table: Q(16x128) @ relkT(64x128)^T -> qrl[16][64]
    {
        f32x4 a;
#pragma unroll
        for (int j = 0; j < 4; ++j) a[j] = 0.f;
#pragma unroll
        for (int ks = 0; ks < 4; ++ks) {
            const bf16x8 bfr = *(const bf16x8*)(relkT + (long)(w * 16 + r16) * NDK + ks * 32 + kq);
            a = __builtin_amdgcn_mfma_f32_16x16x32_bf16(qf[ks], bfr, a, 0, 0, 0);
        }
#pragma unroll
        for (int j = 0; j < 4; ++j)
            qrl[(lane >> 4) * 4 + j][w * 16 + (lane & 15)] = a[j];
    }
    for (int idx = t; idx < QT * 68; idx += 256) ((float*)bins)[idx] = 0.f;

    // --- scores: K-tiles of 64, counted-vmcnt dual buffer
    auto KSTAGE = [&](__bf16* ksb, int kv0) {
#pragma unroll
        for (int ii = 0; ii < 4; ++ii) {
            const int Lc = (w * 4 + ii) * 64 + lane;
            const int j = Lc >> 4, cc = Lc & 15;
            gload16(qkvb + ((long)(b * NS + kv0 + j)) * (3 * ND) + ND + h * NDK + ((cc ^ (j & 7)) << 3),
                    (void*)&ksb[(w * 4 + ii) * 512]);
        }
    };
    auto SCOMP = [&](const __bf16* ksb, int kv0) {
        f32x4 s;
#pragma unroll
        for (int j = 0; j < 4; ++j) s[j] = 0.f;
#pragma unroll
        for (int ks = 0; ks < 4; ++ks) {
            const bf16x8 bfr = *(const bf16x8*)&ksb[(w * 16 + r16) * NDK + ((ks * 32 + kq) ^ xorE)];
            s = __builtin_amdgcn_mfma_f32_16x16x32_bf16(qf[ks], bfr, s, 0, 0, 0);
        }
        const int colb = kv0 + w * 16 + (lane & 15);
#pragma unroll
        for (int j = 0; j < 4; ++j)
            Sl[((lane >> 4) * 4 + j) * SLB + colb] = (__bf16)s[j];
    };

    KSTAGE(Ks0, 0);
    KSTAGE(Ks1, 64);
    for (int tt = 0; tt < 8; tt += 2) {
        asm volatile("s_waitcnt vmcnt(4)\n\ts_barrier" ::: "memory");
        SCOMP(Ks0, tt * 64);
        asm volatile("s_waitcnt lgkmcnt(0)\n\ts_barrier" ::: "memory");
        const bool more = (tt + 2 < 8);
        if (more) {
            KSTAGE(Ks0, (tt + 2) * 64);
            asm volatile("s_waitcnt vmcnt(4)\n\ts_barrier" ::: "memory");
        } else {
            asm volatile("s_waitcnt vmcnt(0)\n\ts_barrier" ::: "memory");
        }
        SCOMP(Ks1, (tt + 1) * 64);
        asm volatile("s_waitcnt lgkmcnt(0)\n\ts_barrier" ::: "memory");
        if (more) KSTAGE(Ks1, (tt + 3) * 64);
    }

    // --- prefetch V tiles 0,1 into the (now free) K buffers; softmax hides them
    auto VSTAGE = [&](__bf16* vs, int kv0) {
#pragma unroll
        for (int ii = 0; ii < 4; ++ii) {
            const int d = w * 32 + ii * 8 + (lane >> 3);
            const int cc = lane & 7;
            gload16(vt + ((long)bh * NDK + d) * NS + kv0 + ((cc ^ (d & 7)) << 3),
                    (void*)&vs[(w * 32 + ii * 8) * 64]);
        }
    };
    VSTAGE(Ks0, 0);
    VSTAGE(Ks1, 64);

    // --- softmax: wave w rows 4w..4w+3; lane owns j = lane*8..lane*8+7
    const float sc = 0.088388347648318447f;  // 1/sqrt(128)
    float lsum = 0.f;
#pragma unroll
    for (int rr = 0; rr < 4; ++rr) {
        const int row = w * 4 + rr;
        const bf16x8 sv = *(const bf16x8*)&Sl[row * SLB + lane * 8];
        int rl[8], mm[8];
        rl[0] = ra[rr][0].x; rl[1] = ra[rr][0].y; rl[2] = ra[rr][0].z; rl[3] = ra[rr][0].w;
        rl[4] = ra[rr][1].x; rl[5] = ra[rr][1].y; rl[6] = ra[rr][1].z; rl[7] = ra[rr][1].w;
        mm[0] = ma[rr][0].x; mm[1] = ma[rr][0].y; mm[2] = ma[rr][0].z; mm[3] = ma[rr][0].w;
        mm[4] = ma[rr][1].x; mm[5] = ma[rr][1].y; mm[6] = ma[rr][1].z; mm[7] = ma[rr][1].w;
        float v[8];
        float mx = -1e30f;
#pragma unroll
        for (int q = 0; q < 8; ++q) {
            float vv = ((float)sv[q] + qrl[row][rl[q]]) * sc;
            if (mm[q] == 0) vv = -1e9f;
            v[q] = vv;
            mx = fmaxf(mx, vv);
        }
#pragma unroll
        for (int of = 32; of > 0; of >>= 1) mx = fmaxf(mx, __shfl_xor(mx, of, 64));
        float sm = 0.f;
#pragma unroll
        for (int q = 0; q < 8; ++q) { v[q] = __expf(v[q] - mx); sm += v[q]; }
#pragma unroll
        for (int of = 32; of > 0; of >>= 1) sm += __shfl_xor(sm, of, 64);
        const float inv = 1.f / sm;
        bf16x8 av;
#pragma unroll
        for (int q = 0; q < 8; ++q) {
            const float a = v[q] * inv;
            av[q] = (__bf16)a;
            atomicAdd(&bins[row][rl[q]], a);
            if (lane * 8 + q < sep) lsum += a;
        }
        *(bf16x8*)&Sl[row * SLB + lane * 8] = av;
    }
#pragma unroll
    for (int of = 32; of > 0; of >>= 1) lsum += __shfl_xor(lsum, of, 64);
    if (lane == 0) redl[w] = lsum;
    // drain LDS (attn, bins, redl) and sync; V loads remain in flight
    asm volatile("s_waitcnt lgkmcnt(0)\n\ts_barrier" ::: "memory");
    if (t == 0) loss_part[bh * 32 + qt] = redl[0] + redl[1] + redl[2] + redl[3];

    // --- PV: wave w owns O cols [w*32, w*32+32); dual-buffered V tiles
    f32x4 oacc[2];
#pragma unroll
    for (int nn = 0; nn < 2; ++nn)
#pragma unroll
        for (int j = 0; j < 4; ++j) oacc[nn][j] = 0.f;

    auto PVCOMP = [&](const __bf16* vs, int kv0) {
        __builtin_amdgcn_s_setprio(1);
#pragma unroll
        for (int ks = 0; ks < 2; ++ks) {
            const bf16x8 af = *(const bf16x8*)&Sl[r16 * SLB + kv0 + ks * 32 + kq];
#pragma unroll
            for (int nn = 0; nn < 2; ++nn) {
                const bf16x8 bv = *(const bf16x8*)&vs[(w * 32 + nn * 16 + r16) * 64 + ((ks * 32 + kq) ^ xorE)];
                oacc[nn] = __builtin_amdgcn_mfma_f32_16x16x32_bf16(af, bv, oacc[nn], 0, 0, 0);
            }
        }
        __builtin_amdgcn_s_setprio(0);
    };

    for (int tt = 0; tt < 8; tt += 2) {
        asm volatile("s_waitcnt vmcnt(4)\n\ts_barrier" ::: "memory");
        PVCOMP(Ks0, tt * 64);
        asm volatile("s_waitcnt lgkmcnt(0)\n\ts_barrier" ::: "memory");
        const bool more = (tt + 2 < 8);
        if (more) {
            VSTAGE(Ks0, (tt + 2) * 64);
            asm volatile("s_waitcnt vmcnt(4)\n\ts_barrier" ::: "memory");
        } else {
            asm volatile("s_waitcnt vmcnt(0)\n\ts_barrier" ::: "memory");
        }
        PVCOMP(Ks1, (tt + 1) * 64);
        asm volatile("s_waitcnt lgkmcnt(0)\n\ts_barrier" ::: "memory");
        if (more) VSTAGE(Ks1, (tt + 3) * 64);
    }

    // --- bins @ relvT fold (K = 64)
#pragma unroll
    for (int kc = 0; kc < 2; ++kc) {
        const float4 b0 = *(const float4*)&bins[r16][kc * 32 + kq];
        const float4 b1 = *(const float4*)&bins[r16][kc * 32 + kq + 4];
        bf16x8 af;
        af[0] = (__bf16)b0.x; af[1] = (__bf16)b0.y; af[2] = (__bf16)b0.z; af[3] = (__bf16)b0.w;
        af[4] = (__bf16)b1.x; af[5] = (__bf16)b1.y; af[6] = (__bf16)b1.z; af[7] = (__bf16)b1.w;
#pragma unroll
        for (int nn = 0; nn < 2; ++nn) {
            const bf16x8 bfr = *(const bf16x8*)(relvT + (long)(w * 32 + nn * 16 + r16) * RPAD + kc * 32 + kq);
            oacc[nn] = __builtin_amdgcn_mfma_f32_16x16x32_bf16(af, bfr, oacc[nn], 0, 0, 0);
        }
    }
#pragma unroll
    for (int nn = 0; nn < 2; ++nn)
#pragma unroll
        for (int j = 0; j < 4; ++j) {
            const int row = (lane >> 4) * 4 + j;
            ctxm[((long)(b * NS + i0 + row)) * ND + h * NDK + w * 32 + nn * 16 + (lane & 15)] =
                (__bf16)oacc[nn][j];
        }
}

// ---------------------------------------------------------------------------
// Fused prep: weight transposes + bias pack + relk pad + LN1 (13396 blocks).
// ---------------------------------------------------------------------------
__global__ void prep_weights(
    const float* __restrict__ Wq, const float* __restrict__ Wk,
    const float* __restrict__ Wv, const float* __restrict__ Wo,
    const float* __restrict__ W1, const float* __restrict__ W2,
    const float* __restrict__ relv,
    const float* __restrict__ bq, const float* __restrict__ bk,
    const float* __restrict__ bv, const float* __restrict__ relk,
    const float* __restrict__ x, const float* __restrict__ ln1g,
    const float* __restrict__ ln1b,
    __bf16* __restrict__ WqkvT, __bf16* __restrict__ WoT,
    __bf16* __restrict__ W1T, __bf16* __restrict__ W2T,
    __bf16* __restrict__ relvT, float* __restrict__ biasqkv,
    __bf16* __restrict__ relkT, __bf16* __restrict__ h1, int R)
{
    const int tile = blockIdx.x;
    const int t = threadIdx.y * 32 + threadIdx.x;

    if (tile >= 12372) {   // LN1 row
        const long row = tile - 12372;
        const float* xr = x + row * ND;
        float4 v = reinterpret_cast<const float4*>(xr)[t];
        float s = v.x + v.y + v.z + v.w;
        float s2 = v.x * v.x + v.y * v.y + v.z * v.z + v.w * v.w;
#pragma unroll
        for (int o = 32; o > 0; o >>= 1) {
            s += __shfl_xor(s, o, 64);
            s2 += __shfl_xor(s2, o, 64);
        }
        __shared__ float red[8];
        const int lane = t & 63, wv = t >> 6;
        if (lane == 0) { red[wv] = s; red[4 + wv] = s2; }
        __syncthreads();
        s = red[0] + red[1] + red[2] + red[3];
        s2 = red[4] + red[5] + red[6] + red[7];
        const float mean = s * (1.f / ND);
        const float var = s2 * (1.f / ND) - mean * mean;
        const float rs = rsqrtf(var + 1e-5f);
        const float xv[4] = {v.x, v.y, v.z, v.w};
        bf16x4 o;
#pragma unroll
        for (int j = 0; j < 4; ++j) {
            const int c = t * 4 + j;
            o[j] = (__bf16)((xv[j] - mean) * rs * ln1g[c] + ln1b[c]);
        }
        *(bf16x4*)&h1[row * ND + t * 4] = o;
        return;
    }
    if (tile >= 12296) {   // bias pack + relk pad (flat)
        const int ft = (tile - 12296) * 256 + t;
        if (ft < ND) biasqkv[ft] = bq[ft];
        else if (ft < 2 * ND) biasqkv[ft] = bk[ft - ND];
        else if (ft < 3 * ND) biasqkv[ft] = bv[ft - 2 * ND];
        else {
            const int idx = ft - 3 * ND;
            if (idx < 128 * NDK) {
                const int r = idx / NDK;
                relkT[idx] = (r < R) ? (__bf16)relk[idx] : (__bf16)0.f;
            }
        }
        return;
    }
    const float* src; __bf16* dst;
    int rows_in, cols_in, ldo, kx, ny;
    if (tile < 4096) {
        const int m = tile >> 10, r = tile & 1023;
        kx = r & 31; ny = r >> 5;
        rows_in = 1024; cols_in = 1024; ldo = 1024;
        src = m == 0 ? Wq : m == 1 ? Wk : m == 2 ? Wv : Wo;
        dst = m == 3 ? WoT : WqkvT + (size_t)m * 1024 * 1024;
    } else if (tile < 8192) {
        const int r = tile - 4096;
        kx = r & 31; ny = r >> 5;
        rows_in = 1024; cols_in = 4096; ldo = 1024; src = W1; dst = W1T;
    } else if (tile < 12288) {
        const int r = tile - 8192;
        kx = r & 127; ny = r >> 7;
        rows_in = 4096; cols_in = 1024; ldo = 4096; src = W2; dst = W2T;
    } else {
        const int r = tile - 12288;
        kx = r & 1; ny = r >> 1;
        rows_in = R; cols_in = 128; ldo = 64; src = relv; dst = relvT;
    }

    __shared__ float tl[32][33];
    const int k0 = kx * 32, n0 = ny * 32;
    const int tx = threadIdx.x, ty = threadIdx.y;
#pragma unroll
    for (int dy = 0; dy < 32; dy += 8) {
        const int k = k0 + ty + dy, nn = n0 + tx;
        tl[ty + dy][tx] = (k < rows_in && nn < cols_in) ? src[(long)k * cols_in + nn] : 0.f;
    }
    __syncthreads();
#pragma unroll
    for (int dy = 0; dy < 32; dy += 8) {
        const int nn = n0 + ty + dy, k = k0 + tx;
        if (nn < cols_in && k < ldo) dst[(long)nn * ldo + k] = (__bf16)tl[tx][ty + dy];
    }
}

// Wo split-K(2) reduce + residual + bias, fused LN2 -> out fp32 + h2 bf16.
__global__ __launch_bounds__(256) void wo_reduce_ln(
    const float* __restrict__ P, const float* __restrict__ x,
    const float* __restrict__ bo, const float* __restrict__ g,
    const float* __restrict__ bb, float* __restrict__ out,
    __bf16* __restrict__ h2)
{
    const int row = blockIdx.x;
    const int t = threadIdx.x;
    const long i4 = (long)row * 256 + t;
    const long sP = (long)BSROWS * ND / 4;
    const float4* P4 = (const float4*)P;
    float4 s = P4[i4];
    const float4 t1 = P4[i4 + sP];
    s.x += t1.x; s.y += t1.y; s.z += t1.z; s.w += t1.w;
    const int col = t * 4;
    const float4 xv = ((const float4*)x)[i4];
    const float4 bv = *(const float4*)&bo[col];
    float4 o;
    o.x = s.x + xv.x + bv.x; o.y = s.y + xv.y + bv.y;
    o.z = s.z + xv.z + bv.z; o.w = s.w + xv.w + bv.w;
    ((float4*)out)[i4] = o;

    float sum = o.x + o.y + o.z + o.w;
    float sum2 = o.x * o.x + o.y * o.y + o.z * o.z + o.w * o.w;
#pragma unroll
    for (int of = 32; of > 0; of >>= 1) {
        sum += __shfl_xor(sum, of, 64);
        sum2 += __shfl_xor(sum2, of, 64);
    }
    __shared__ float red[8];
    const int lane = t & 63, wv = t >> 6;
    if (lane == 0) { red[wv] = sum; red[4 + wv] = sum2; }
    __syncthreads();
    sum = red[0] + red[1] + red[2] + red[3];
    sum2 = red[4] + red[5] + red[6] + red[7];
    const float mean = sum * (1.f / ND);
    const float var = sum2 * (1.f / ND) - mean * mean;
    const float rs = rsqrtf(var + 1e-5f);
    const float ov[4] = {o.x, o.y, o.z, o.w};
    bf16x4 hb;
#pragma unroll
    for (int j = 0; j < 4; ++j)
        hb[j] = (__bf16)((ov[j] - mean) * rs * g[col + j] + bb[col + j]);
    *(bf16x4*)&h2[(long)row * ND + col] = hb;
}

// FFN2 split-K(2) reduce: out += b2 + sum_2 partials. Block 0 finalizes loss.
__global__ __launch_bounds__(256) void ffn2_reduce(
    const float* __restrict__ P, const float* __restrict__ b2, float* __restrict__ out,
    const float* __restrict__ loss_part, const float* __restrict__ hist,
    const int* __restrict__ sep_p, float* __restrict__ out_loss)
{
    const int i4 = blockIdx.x * 256 + threadIdx.x;
    const long sP = (long)BSROWS * ND / 4;
    const float4* P4 = (const float4*)P;
    float4 s = P4[i4];
    const float4 t1 = P4[i4 + sP];
    s.x += t1.x; s.y += t1.y; s.z += t1.z; s.w += t1.w;
    const int col = (i4 * 4) & (ND - 1);
    const float4 bv = *(const float4*)&b2[col];
    float4 o = ((float4*)out)[i4];
    o.x += s.x + bv.x; o.y += s.y + bv.y;
    o.z += s.z + bv.z; o.w += s.w + bv.w;
    ((float4*)out)[i4] = o;

    if (blockIdx.x == 0) {
        const int t = threadIdx.x;
        float ls = 0.f;
        if (t < 128) {
            const float4 v = ((const float4*)loss_part)[t];   // 512 floats
            ls = v.x + v.y + v.z + v.w;
        }
#pragma unroll
        for (int of = 32; of > 0; of >>= 1) ls += __shfl_xor(ls, of, 64);
        __shared__ float red[4];
        if ((t & 63) == 0) red[t >> 6] = ls;
        __syncthreads();
        if (t == 0) {
            const int sep = *sep_p;
            const float total = red[0] + red[1] + red[2] + red[3];
            const float denom = (float)NB * NH * NS * (float)(sep > 0 ? sep : 1);
            out_loss[0] = (sep > 0) ? hist[0] * total / denom : 0.f;
        }
    }
}

// ---------------------------------------------------------------------------
extern "C" void kernel_launch(void* const* d_in, const int* in_sizes, int n_in,
                              void* d_out, int out_size, void* d_ws, size_t ws_size,
                              hipStream_t stream)
{
    const float* x      = (const float*)d_in[0];
    const int* relation = (const int*)d_in[1];
    const int* mask     = (const int*)d_in[2];
    const int* sep_p    = (const int*)d_in[3];
    const float* hist   = (const float*)d_in[4];
    const float* Wq = (const float*)d_in[5],  *bq = (const float*)d_in[6];
    const float* Wk = (const float*)d_in[7],  *bk = (const float*)d_in[8];
    const float* Wv = (const float*)d_in[9],  *bv = (const float*)d_in[10];
    const float* Wo = (const float*)d_in[11], *bo = (const float*)d_in[12];
    const float* relk = (const float*)d_in[13];
    const float* relv = (const float*)d_in[14];
    const float* ln1g = (const float*)d_in[15], *ln1b = (const float*)d_in[16];
    const float* ln2g = (const float*)d_in[17], *ln2b = (const float*)d_in[18];
    const float* W1 = (const float*)d_in[19], *b1 = (const float*)d_in[20];
    const float* W2 = (const float*)d_in[21], *b2 = (const float*)d_in[22];
    const int R = in_sizes[13] / NDK;  // 51

    float* out = (float*)d_out;
    float* out_loss = out + (long)BSROWS * ND;

    char* p = (char*)d_ws;
    auto alloc = [&](size_t bytes) -> void* {
        void* r = (void*)p;
        p += (bytes + 255) & ~(size_t)255;
        return r;
    };
    __bf16* WqkvT   = (__bf16*)alloc((size_t)3 * ND * ND * 2);
    __bf16* WoT     = (__bf16*)alloc((size_t)ND * ND * 2);
    __bf16* W1T     = (__bf16*)alloc((size_t)NDFF * ND * 2);
    __bf16* W2T     = (__bf16*)alloc((size_t)ND * NDFF * 2);
    __bf16* relkT   = (__bf16*)alloc((size_t)128 * NDK * 2);
    __bf16* relvT   = (__bf16*)alloc((size_t)NDK * RPAD * 2);
    float*  biasqkv = (float*)alloc((size_t)3 * ND * 4);
    __bf16* h1      = (__bf16*)alloc((size_t)BSROWS * ND * 2);
    __bf16* qkvb    = (__bf16*)alloc((size_t)BSROWS * 3 * ND * 2);
    __bf16* vt      = (__bf16*)alloc((size_t)NBH * NDK * NS * 2);
    __bf16* ctxm    = (__bf16*)alloc((size_t)BSROWS * ND * 2);
    __bf16* h2      = (__bf16*)alloc((size_t)BSROWS * ND * 2);
    __bf16* F1      = (__bf16*)alloc((size_t)BSROWS * NDFF * 2);
    float*  loss_part = (float*)alloc((size_t)512 * 4);
    float*  arena   = (float*)alloc((size_t)16 * 1024 * 1024);
    float* woPart   = arena;                            // 8 MB
    float* f2Part   = arena + (size_t)2 * 1024 * 1024;  // 8 MB

    const dim3 tb(32, 8);
    prep_weights<<<13396, tb, 0, stream>>>(Wq, Wk, Wv, Wo, W1, W2, relv,
                                           bq, bk, bv, relk, x, ln1g, ln1b,
                                           WqkvT, WoT, W1T, W2T, relvT,
                                           biasqkv, relkT, h1, R);

    // QKV + fused V-transpose (768 blocks, nt=16)
    gemm64<<<dim3(48, 16, 1), 256, 0, stream>>>(
        h1, WqkvT, vt, nullptr, qkvb, biasqkv,
        ND, ND, ND, 3 * ND,
        0, 0, 1, 0, 0, 1, 0, 1, 0, 8);

    // fused attention middle (512 blocks)
    attn_fused<<<dim3(32, 16), 256, 0, stream>>>(
        qkvb, vt, relkT, relvT, relation, mask, ctxm, loss_part, sep_p);

    // attn_out partials: ctxm @ Wo, split-K x2 (Ksp=512, nt=8), 512 blocks
    gemm64<<<dim3(16, 16, 2), 256, 0, stream>>>(
        ctxm, WoT, nullptr, woPart, nullptr, nullptr,
        512, ND, ND, ND,
        0, 0, 1, 0, 0, 1,
        0, 2, (long)BSROWS * ND, 0);

    wo_reduce_ln<<<BSROWS, 256, 0, stream>>>(woPart, x, bo, ln2g, ln2b, out, h2);

    // FFN1: relu(h2 @ W1 + b1) -> F1 bf16 (1024 blocks, nt=16)
    gemm64<<<dim3(64, 16, 1), 256, 0, stream>>>(
        h2, W1T, nullptr, nullptr, F1, b1,
        ND, ND, ND, NDFF,
        0, 0, 1, 0, 0, 1, 0, 1, 0, 1);

    // FFN2 partials: F1 @ W2, split-K x2 (Ksp=2048, nt=32), 512 blocks
    gemm64<<<dim3(16, 16, 2), 256, 0, stream>>>(
        F1, W2T, nullptr, f2Part, nullptr, nullptr,
        2048, NDFF, NDFF, ND,
        0, 0, 1, 0, 0, 1,
        0, 2, (long)BSROWS * ND, 0);

    ffn2_reduce<<<1024, 256, 0, stream>>>(f2Part, b2, out,
                                          loss_part, hist, sep_p, out_loss);
}